// Round 3
// baseline (1168.793 us; speedup 1.0000x reference)
//
#include <hip/hip_runtime.h>
#include <hip/hip_bf16.h>
#include <math.h>

// SigmaMoE: T=4096 tokens, H=1024, I=512, E=16 experts, top-2, shared IS=1024.
// Inputs/outputs FLOAT32; internal GEMMs bf16 MFMA 32x32x16, direct-from-global
// fragments (no LDS, no barriers in GEMM K-loops).
#define H_DIM 1024
#define I_DIM 512
#define E_NUM 16
#define T_TOK 4096
#define IS_DIM 1024

typedef unsigned short u16;
typedef __attribute__((ext_vector_type(8))) short short8;     // 8 x bf16 frag (16B)
typedef __attribute__((ext_vector_type(16))) float floatx16;  // 32x32 acc

__device__ __forceinline__ float bf2f(u16 u) {
    union { unsigned int u; float f; } c; c.u = ((unsigned int)u) << 16; return c.f;
}
__device__ __forceinline__ u16 f2bf(float f) {
    union { float f; unsigned int u; } c; c.f = f;
    unsigned int r = (c.u + 0x7fffu + ((c.u >> 16) & 1u)) >> 16;
    return (u16)r;
}

// ---------------------------------------------------------------------------
// Weight convert+transpose: f32 K-major -> bf16 N-major (contiguous K per row),
// 64x64 tiles via LDS. 6912 blocks. (unchanged from R2 — works, ~HBM-bound)
// ---------------------------------------------------------------------------
__global__ __launch_bounds__(256)
void k_transpose(const float* wg, const float* wu, const float* wd,
                 const float* sg, const float* su, const float* sd,
                 u16* wgt, u16* wut, u16* wdt, u16* sgt, u16* sut, u16* sdt)
{
    int bx = blockIdx.x;
    const float* src; u16* dst; int R, C, local;
    if (bx < 2048)      { src = wg; dst = wgt; R = 1024; C = 512;  local = bx; }
    else if (bx < 4096) { src = wu; dst = wut; R = 1024; C = 512;  local = bx - 2048; }
    else if (bx < 6144) { src = wd; dst = wdt; R = 512;  C = 1024; local = bx - 4096; }
    else if (bx < 6400) { src = sg; dst = sgt; R = 1024; C = 1024; local = bx - 6144; }
    else if (bx < 6656) { src = su; dst = sut; R = 1024; C = 1024; local = bx - 6400; }
    else                { src = sd; dst = sdt; R = 1024; C = 1024; local = bx - 6656; }
    int tpm = (R >> 6) * (C >> 6);
    int mat = local / tpm;
    int tl_ = local - mat * tpm;
    int tcn = C >> 6;
    int tr = tl_ / tcn, tc = tl_ - (tl_ / tcn) * tcn;
    src += (size_t)mat * R * C;
    dst += (size_t)mat * R * C;

    __shared__ u16 tile[64][65];
    int t = threadIdx.x;
    int r0 = t >> 2, c0 = (t & 3) * 16;
    const float* sp = src + (size_t)(tr * 64 + r0) * C + tc * 64 + c0;
    #pragma unroll
    for (int j = 0; j < 16; j += 4) {
        float4 v = *(const float4*)(sp + j);
        tile[r0][c0 + j + 0] = f2bf(v.x);
        tile[r0][c0 + j + 1] = f2bf(v.y);
        tile[r0][c0 + j + 2] = f2bf(v.z);
        tile[r0][c0 + j + 3] = f2bf(v.w);
    }
    __syncthreads();
    int cW = t >> 2, rW = (t & 3) * 16;
    u16 tmp[16];
    #pragma unroll
    for (int j = 0; j < 16; ++j) tmp[j] = tile[rW + j][cW];
    u16* dp = dst + (size_t)(tc * 64 + cW) * R + tr * 64 + rW;
    *(uint4*)(dp)     = *(const uint4*)(tmp);
    *(uint4*)(dp + 8) = *(const uint4*)(tmp + 8);
}

// f32 -> bf16 copy of x (A-operand rows).
__global__ __launch_bounds__(256)
void k_xconv(const float* x, u16* xb)
{
    int i = blockIdx.x * 256 + threadIdx.x;
    float4 v = ((const float4*)x)[i];
    u16 o[4] = { f2bf(v.x), f2bf(v.y), f2bf(v.z), f2bf(v.w) };
    ((uint2*)xb)[i] = *(const uint2*)o;
}

// ---------------------------------------------------------------------------
// Router (unchanged): w1 = 1/(1+exp(s2-s1)); per-expert lists via atomics.
// ---------------------------------------------------------------------------
__global__ __launch_bounds__(256)
void k_router(const float* x, const float* rw, float* topkw, int* elist, int* cnt)
{
    int lane = threadIdx.x & 63;
    int wv = threadIdx.x >> 6;
    int t = blockIdx.x * 4 + wv;
    const float* xr = x + (size_t)t * H_DIM;
    float xv[16];
    #pragma unroll
    for (int j = 0; j < 16; ++j) xv[j] = xr[j * 64 + lane];
    float sc[E_NUM];
    #pragma unroll
    for (int e = 0; e < E_NUM; ++e) {
        const float* rr = rw + e * H_DIM;
        float s = 0.f;
        #pragma unroll
        for (int j = 0; j < 16; ++j) s += xv[j] * rr[j * 64 + lane];
        #pragma unroll
        for (int off = 32; off > 0; off >>= 1) s += __shfl_xor(s, off, 64);
        sc[e] = s;
    }
    if (lane == 0) {
        float b1 = -1e30f, b2 = -1e30f; int i1 = 0, i2 = 0;
        #pragma unroll
        for (int e = 0; e < E_NUM; ++e) {
            if (sc[e] > b1) { b2 = b1; i2 = i1; b1 = sc[e]; i1 = e; }
            else if (sc[e] > b2) { b2 = sc[e]; i2 = e; }
        }
        float w1 = 1.f / (1.f + __expf(b2 - b1));
        float w2 = 1.f - w1;
        topkw[t * 2]     = w1;
        topkw[t * 2 + 1] = w2;
        int p1 = atomicAdd(&cnt[i1], 1); elist[i1 * T_TOK + p1] = (t << 1);
        int p2 = atomicAdd(&cnt[i2], 1); elist[i2 * T_TOK + p2] = (t << 1) | 1;
    }
}

// Padded (to 128) exclusive prefix over counts -> act-buffer row bases.
__global__ void k_prefix(const int* cnt, int* base)
{
    if (threadIdx.x == 0) {
        int b = 0;
        for (int e = 0; e < E_NUM; ++e) { base[e] = b; b += ((cnt[e] + 127) >> 7) << 7; }
    }
}

// ---------------------------------------------------------------------------
// Routed gate/up GEMM. Block = 128 rows x 64 act-cols; 4 waves in 2x2:
// wave = 64 rows x 32 cols, acc = {g,u} x 2 m-tiles of 32x32.
// Direct global->reg frags, K-loop is pure loads+MFMA (offsets immediate).
// ---------------------------------------------------------------------------
__global__ __launch_bounds__(256)
void k_expert_gateup(const u16* xb, const u16* wgt, const u16* wut,
                     const int* elist, const int* cnt, const int* base, u16* act)
{
    int e = blockIdx.x >> 5;        // 32 m-tiles of 128 max per expert
    int mt = blockIdx.x & 31;
    int c = cnt[e];
    if (mt * 128 >= c) return;
    int cb = blockIdx.y;            // 0..7: 64-col block of I

    int tid = threadIdx.x, lane = tid & 63, w = tid >> 6;
    int wr = w >> 1, wc = w & 1;
    int l31 = lane & 31, h = lane >> 5;
    int m0 = mt * 128 + wr * 64;
    int c0 = cb * 64 + wc * 32;

    const u16* aptr[2];
    #pragma unroll
    for (int t2 = 0; t2 < 2; ++t2) {
        int p = m0 + t2 * 32 + l31;
        int pc = p < c ? p : c - 1;            // clamp pad rows to a valid token
        int tok = elist[e * T_TOK + pc] >> 1;
        aptr[t2] = xb + (size_t)tok * H_DIM + h * 8;
    }
    const u16* gptr = wgt + ((size_t)e * I_DIM + c0 + l31) * H_DIM + h * 8;
    const u16* uptr = wut + ((size_t)e * I_DIM + c0 + l31) * H_DIM + h * 8;

    floatx16 accg[2], accu[2];
    #pragma unroll
    for (int i = 0; i < 2; ++i)
        #pragma unroll
        for (int r = 0; r < 16; ++r) { accg[i][r] = 0.f; accu[i][r] = 0.f; }

    #pragma unroll 4
    for (int s = 0; s < H_DIM / 16; ++s) {
        short8 bg = *(const short8*)(gptr + s * 16);
        short8 bu = *(const short8*)(uptr + s * 16);
        #pragma unroll
        for (int t2 = 0; t2 < 2; ++t2) {
            short8 a = *(const short8*)(aptr[t2] + s * 16);
            accg[t2] = __builtin_amdgcn_mfma_f32_32x32x16_bf16(a, bg, accg[t2], 0, 0, 0);
            accu[t2] = __builtin_amdgcn_mfma_f32_32x32x16_bf16(a, bu, accu[t2], 0, 0, 0);
        }
    }

    int abase = base[e] + m0;
    #pragma unroll
    for (int t2 = 0; t2 < 2; ++t2) {
        #pragma unroll
        for (int r = 0; r < 16; ++r) {
            int row = t2 * 32 + (r & 3) + 4 * h + 8 * (r >> 2);
            float g = accg[t2][r], u = accu[t2][r];
            float a = g / (1.f + __expf(-g)) * u;        // silu(g)*u
            act[(size_t)(abase + row) * I_DIM + c0 + l31] = f2bf(a);
        }
    }
}

// ---------------------------------------------------------------------------
// Routed down GEMM. Block = 128 rows x 128 H-cols; wave = 64x64 (2x2 of 32x32).
// Scatter rows (scaled by routing weight) into y0/y1 slot buffers.
// ---------------------------------------------------------------------------
__global__ __launch_bounds__(256)
void k_expert_down(const u16* act, const u16* wdt, const int* elist,
                   const int* cnt, const int* base, const float* topkw,
                   u16* y0, u16* y1)
{
    int e = blockIdx.x >> 5;
    int mt = blockIdx.x & 31;
    int c = cnt[e];
    if (mt * 128 >= c) return;
    int nb = blockIdx.y;            // 0..7: 128-col block of H

    int tid = threadIdx.x, lane = tid & 63, w = tid >> 6;
    int wr = w >> 1, wc = w & 1;
    int l31 = lane & 31, h = lane >> 5;
    int m0 = mt * 128 + wr * 64;
    int n0 = nb * 128 + wc * 64;

    const u16* aptr[2];
    const u16* bptr[2];
    #pragma unroll
    for (int t2 = 0; t2 < 2; ++t2) {
        aptr[t2] = act + (size_t)(base[e] + m0 + t2 * 32 + l31) * I_DIM + h * 8;
        bptr[t2] = wdt + ((size_t)e * H_DIM + n0 + t2 * 32 + l31) * I_DIM + h * 8;
    }

    floatx16 acc[2][2];
    #pragma unroll
    for (int i = 0; i < 2; ++i)
        #pragma unroll
        for (int j = 0; j < 2; ++j)
            #pragma unroll
            for (int r = 0; r < 16; ++r) acc[i][j][r] = 0.f;

    #pragma unroll 4
    for (int s = 0; s < I_DIM / 16; ++s) {
        short8 b0 = *(const short8*)(bptr[0] + s * 16);
        short8 b1 = *(const short8*)(bptr[1] + s * 16);
        #pragma unroll
        for (int t2 = 0; t2 < 2; ++t2) {
            short8 a = *(const short8*)(aptr[t2] + s * 16);
            acc[t2][0] = __builtin_amdgcn_mfma_f32_32x32x16_bf16(a, b0, acc[t2][0], 0, 0, 0);
            acc[t2][1] = __builtin_amdgcn_mfma_f32_32x32x16_bf16(a, b1, acc[t2][1], 0, 0, 0);
        }
    }

    #pragma unroll
    for (int t2 = 0; t2 < 2; ++t2) {
        #pragma unroll
        for (int r = 0; r < 16; ++r) {
            int row = t2 * 32 + (r & 3) + 4 * h + 8 * (r >> 2);
            int p = m0 + row;
            if (p < c) {
                int ent = elist[e * T_TOK + p];
                int t = ent >> 1, sl = ent & 1;
                float wgt_ = topkw[t * 2 + sl];
                u16* yb = sl ? y1 : y0;
                #pragma unroll
                for (int n2 = 0; n2 < 2; ++n2)
                    yb[(size_t)t * H_DIM + n0 + n2 * 32 + l31] = f2bf(wgt_ * acc[t2][n2][r]);
            }
        }
    }
}

// ---------------------------------------------------------------------------
// Shared gate/up: dense rows. Block = 128 rows x 64 IS-cols (2x2 waves).
// ---------------------------------------------------------------------------
__global__ __launch_bounds__(256)
void k_shared_gateup(const u16* xb, const u16* sgt, const u16* sut, u16* sact)
{
    int tid = threadIdx.x, lane = tid & 63, w = tid >> 6;
    int wr = w >> 1, wc = w & 1;
    int l31 = lane & 31, h = lane >> 5;
    int m0 = blockIdx.x * 128 + wr * 64;           // 0..31 blocks
    int c0 = blockIdx.y * 64 + wc * 32;            // 0..15 blocks

    const u16* aptr[2];
    #pragma unroll
    for (int t2 = 0; t2 < 2; ++t2)
        aptr[t2] = xb + (size_t)(m0 + t2 * 32 + l31) * H_DIM + h * 8;
    const u16* gptr = sgt + (size_t)(c0 + l31) * H_DIM + h * 8;
    const u16* uptr = sut + (size_t)(c0 + l31) * H_DIM + h * 8;

    floatx16 accg[2], accu[2];
    #pragma unroll
    for (int i = 0; i < 2; ++i)
        #pragma unroll
        for (int r = 0; r < 16; ++r) { accg[i][r] = 0.f; accu[i][r] = 0.f; }

    #pragma unroll 4
    for (int s = 0; s < H_DIM / 16; ++s) {
        short8 bg = *(const short8*)(gptr + s * 16);
        short8 bu = *(const short8*)(uptr + s * 16);
        #pragma unroll
        for (int t2 = 0; t2 < 2; ++t2) {
            short8 a = *(const short8*)(aptr[t2] + s * 16);
            accg[t2] = __builtin_amdgcn_mfma_f32_32x32x16_bf16(a, bg, accg[t2], 0, 0, 0);
            accu[t2] = __builtin_amdgcn_mfma_f32_32x32x16_bf16(a, bu, accu[t2], 0, 0, 0);
        }
    }

    #pragma unroll
    for (int t2 = 0; t2 < 2; ++t2) {
        #pragma unroll
        for (int r = 0; r < 16; ++r) {
            int row = m0 + t2 * 32 + (r & 3) + 4 * h + 8 * (r >> 2);
            float g = accg[t2][r], u = accu[t2][r];
            float a = g / (1.f + __expf(-g)) * u;
            sact[(size_t)row * IS_DIM + c0 + l31] = f2bf(a);
        }
    }
}

// ---------------------------------------------------------------------------
// Shared down + final combine: out f32 = sact@sd + y0 + y1.
// Block = 128 rows x 128 H-cols (2x2 waves of 64x64). K=1024.
// ---------------------------------------------------------------------------
__global__ __launch_bounds__(256)
void k_shared_down(const u16* sact, const u16* sdt, const u16* y0, const u16* y1,
                   float* out)
{
    int tid = threadIdx.x, lane = tid & 63, w = tid >> 6;
    int wr = w >> 1, wc = w & 1;
    int l31 = lane & 31, h = lane >> 5;
    int m0 = blockIdx.x * 128 + wr * 64;           // 0..31
    int n0 = blockIdx.y * 128 + wc * 64;           // 0..7

    const u16* aptr[2];
    const u16* bptr[2];
    #pragma unroll
    for (int t2 = 0; t2 < 2; ++t2) {
        aptr[t2] = sact + (size_t)(m0 + t2 * 32 + l31) * IS_DIM + h * 8;
        bptr[t2] = sdt  + (size_t)(n0 + t2 * 32 + l31) * IS_DIM + h * 8;
    }

    floatx16 acc[2][2];
    #pragma unroll
    for (int i = 0; i < 2; ++i)
        #pragma unroll
        for (int j = 0; j < 2; ++j)
            #pragma unroll
            for (int r = 0; r < 16; ++r) acc[i][j][r] = 0.f;

    #pragma unroll 4
    for (int s = 0; s < IS_DIM / 16; ++s) {
        short8 b0 = *(const short8*)(bptr[0] + s * 16);
        short8 b1 = *(const short8*)(bptr[1] + s * 16);
        #pragma unroll
        for (int t2 = 0; t2 < 2; ++t2) {
            short8 a = *(const short8*)(aptr[t2] + s * 16);
            acc[t2][0] = __builtin_amdgcn_mfma_f32_32x32x16_bf16(a, b0, acc[t2][0], 0, 0, 0);
            acc[t2][1] = __builtin_amdgcn_mfma_f32_32x32x16_bf16(a, b1, acc[t2][1], 0, 0, 0);
        }
    }

    #pragma unroll
    for (int t2 = 0; t2 < 2; ++t2) {
        #pragma unroll
        for (int r = 0; r < 16; ++r) {
            int row = m0 + t2 * 32 + (r & 3) + 4 * h + 8 * (r >> 2);
            #pragma unroll
            for (int n2 = 0; n2 < 2; ++n2) {
                int col = n0 + n2 * 32 + l31;
                float v = acc[t2][n2][r] + bf2f(y0[(size_t)row * H_DIM + col])
                                         + bf2f(y1[(size_t)row * H_DIM + col]);
                out[(size_t)row * H_DIM + col] = v;
            }
        }
    }
}

// ---------------------------------------------------------------------------
extern "C" void kernel_launch(void* const* d_in, const int* in_sizes, int n_in,
                              void* d_out, int out_size, void* d_ws, size_t ws_size,
                              hipStream_t stream)
{
    const float* x  = (const float*)d_in[0];
    const float* rw = (const float*)d_in[1];
    const float* wg = (const float*)d_in[2];
    const float* wu = (const float*)d_in[3];
    const float* wd = (const float*)d_in[4];
    const float* sg = (const float*)d_in[5];
    const float* su = (const float*)d_in[6];
    const float* sd = (const float*)d_in[7];
    float* out = (float*)d_out;

    char* ws = (char*)d_ws;
    const size_t MB = 1024ull * 1024ull;
    u16* wgt  = (u16*)(ws);            // [E][I][H] bf16  16 MB
    u16* wut  = (u16*)(ws + 16 * MB);  // [E][I][H]       16 MB
    u16* wdt  = (u16*)(ws + 32 * MB);  // [E][H][I]       16 MB
    u16* sgt  = (u16*)(ws + 48 * MB);  // [IS][H]          2 MB
    u16* sut  = (u16*)(ws + 50 * MB);  // [IS][H]          2 MB
    u16* sdt  = (u16*)(ws + 52 * MB);  // [H][IS]          2 MB
    u16* xb   = (u16*)(ws + 54 * MB);  // [T][H] bf16      8 MB
    u16* act  = (u16*)(ws + 62 * MB);  // [<=10240][I]    10 MB (128-padded rows)
    u16* sact = (u16*)(ws + 72 * MB);  // [T][IS]          8 MB
    u16* y0   = (u16*)(ws + 80 * MB);  // [T][H] slot0     8 MB
    u16* y1   = (u16*)(ws + 88 * MB);  // [T][H] slot1     8 MB
    float* topkw = (float*)(ws + 96 * MB);          // [T][2]
    int* elist   = (int*)(ws + 96 * MB + 64 * 1024);// [E][T]
    int* cnt     = (int*)(ws + 97 * MB);            // [E]
    int* base    = (int*)(ws + 97 * MB + 256);      // [E]

    hipMemsetAsync(cnt, 0, E_NUM * sizeof(int), stream);
    k_transpose<<<6912, 256, 0, stream>>>(wg, wu, wd, sg, su, sd,
                                          wgt, wut, wdt, sgt, sut, sdt);
    k_xconv<<<T_TOK * H_DIM / 4 / 256, 256, 0, stream>>>(x, xb);
    k_router<<<T_TOK / 4, 256, 0, stream>>>(x, rw, topkw, elist, cnt);
    k_prefix<<<1, 64, 0, stream>>>(cnt, base);
    k_expert_gateup<<<dim3(E_NUM * 32, I_DIM / 64), 256, 0, stream>>>(
        xb, wgt, wut, elist, cnt, base, act);
    k_expert_down<<<dim3(E_NUM * 32, H_DIM / 128), 256, 0, stream>>>(
        act, wdt, elist, cnt, base, topkw, y0, y1);
    k_shared_gateup<<<dim3(T_TOK / 128, IS_DIM / 64), 256, 0, stream>>>(
        xb, sgt, sut, sact);
    k_shared_down<<<dim3(T_TOK / 128, H_DIM / 128), 256, 0, stream>>>(
        sact, sdt, y0, y1, out);
}

// Round 4
// 570.822 us; speedup vs baseline: 2.0476x; 2.0476x over previous
//
#include <hip/hip_runtime.h>
#include <hip/hip_bf16.h>
#include <math.h>

// SigmaMoE: T=4096 tokens, H=1024, I=512, E=16 experts, top-2, shared IS=1024.
// Inputs/outputs FLOAT32; internal GEMMs bf16 MFMA 16x16x32, 128x128 tiles,
// global_load_lds width-16 staging, XOR-swizzled LDS chunks (conflict-free).
#define H_DIM 1024
#define I_DIM 512
#define E_NUM 16
#define T_TOK 4096
#define IS_DIM 1024

typedef unsigned short u16;
typedef __attribute__((ext_vector_type(8))) short short8;   // 8 x bf16 frag (16B)
typedef __attribute__((ext_vector_type(4))) float floatx4;  // 16x16 acc

__device__ __forceinline__ float bf2f(u16 u) {
    union { unsigned int u; float f; } c; c.u = ((unsigned int)u) << 16; return c.f;
}
__device__ __forceinline__ u16 f2bf(float f) {
    union { float f; unsigned int u; } c; c.f = f;
    unsigned int r = (c.u + 0x7fffu + ((c.u >> 16) & 1u)) >> 16;
    return (u16)r;
}
// async global->LDS, 16B per lane; LDS dest = wave-uniform base + lane*16.
__device__ __forceinline__ void gld16(const u16* g, u16* l) {
    __builtin_amdgcn_global_load_lds(
        (const __attribute__((address_space(1))) unsigned int*)g,
        (__attribute__((address_space(3))) unsigned int*)l, 16, 0, 0);
}

// ---------------------------------------------------------------------------
// Weight convert+transpose: f32 K-major -> bf16 N-major. (unchanged, works)
// ---------------------------------------------------------------------------
__global__ __launch_bounds__(256)
void k_transpose(const float* wg, const float* wu, const float* wd,
                 const float* sg, const float* su, const float* sd,
                 u16* wgt, u16* wut, u16* wdt, u16* sgt, u16* sut, u16* sdt)
{
    int bx = blockIdx.x;
    const float* src; u16* dst; int R, C, local;
    if (bx < 2048)      { src = wg; dst = wgt; R = 1024; C = 512;  local = bx; }
    else if (bx < 4096) { src = wu; dst = wut; R = 1024; C = 512;  local = bx - 2048; }
    else if (bx < 6144) { src = wd; dst = wdt; R = 512;  C = 1024; local = bx - 4096; }
    else if (bx < 6400) { src = sg; dst = sgt; R = 1024; C = 1024; local = bx - 6144; }
    else if (bx < 6656) { src = su; dst = sut; R = 1024; C = 1024; local = bx - 6400; }
    else                { src = sd; dst = sdt; R = 1024; C = 1024; local = bx - 6656; }
    int tpm = (R >> 6) * (C >> 6);
    int mat = local / tpm;
    int tl_ = local - mat * tpm;
    int tcn = C >> 6;
    int tr = tl_ / tcn, tc = tl_ - (tl_ / tcn) * tcn;
    src += (size_t)mat * R * C;
    dst += (size_t)mat * R * C;

    __shared__ u16 tile[64][65];
    int t = threadIdx.x;
    int r0 = t >> 2, c0 = (t & 3) * 16;
    const float* sp = src + (size_t)(tr * 64 + r0) * C + tc * 64 + c0;
    #pragma unroll
    for (int j = 0; j < 16; j += 4) {
        float4 v = *(const float4*)(sp + j);
        tile[r0][c0 + j + 0] = f2bf(v.x);
        tile[r0][c0 + j + 1] = f2bf(v.y);
        tile[r0][c0 + j + 2] = f2bf(v.z);
        tile[r0][c0 + j + 3] = f2bf(v.w);
    }
    __syncthreads();
    int cW = t >> 2, rW = (t & 3) * 16;
    u16 tmp[16];
    #pragma unroll
    for (int j = 0; j < 16; ++j) tmp[j] = tile[rW + j][cW];
    u16* dp = dst + (size_t)(tc * 64 + cW) * R + tr * 64 + rW;
    *(uint4*)(dp)     = *(const uint4*)(tmp);
    *(uint4*)(dp + 8) = *(const uint4*)(tmp + 8);
}

// f32 -> bf16 copy of x.
__global__ __launch_bounds__(256)
void k_xconv(const float* x, u16* xb)
{
    int i = blockIdx.x * 256 + threadIdx.x;
    float4 v = ((const float4*)x)[i];
    u16 o[4] = { f2bf(v.x), f2bf(v.y), f2bf(v.z), f2bf(v.w) };
    ((uint2*)xb)[i] = *(const uint2*)o;
}

// ---------------------------------------------------------------------------
// Router (unchanged, works).
// ---------------------------------------------------------------------------
__global__ __launch_bounds__(256)
void k_router(const float* x, const float* rw, float* topkw, int* elist, int* cnt)
{
    int lane = threadIdx.x & 63;
    int wv = threadIdx.x >> 6;
    int t = blockIdx.x * 4 + wv;
    const float* xr = x + (size_t)t * H_DIM;
    float xv[16];
    #pragma unroll
    for (int j = 0; j < 16; ++j) xv[j] = xr[j * 64 + lane];
    float sc[E_NUM];
    #pragma unroll
    for (int e = 0; e < E_NUM; ++e) {
        const float* rr = rw + e * H_DIM;
        float s = 0.f;
        #pragma unroll
        for (int j = 0; j < 16; ++j) s += xv[j] * rr[j * 64 + lane];
        #pragma unroll
        for (int off = 32; off > 0; off >>= 1) s += __shfl_xor(s, off, 64);
        sc[e] = s;
    }
    if (lane == 0) {
        float b1 = -1e30f, b2 = -1e30f; int i1 = 0, i2 = 0;
        #pragma unroll
        for (int e = 0; e < E_NUM; ++e) {
            if (sc[e] > b1) { b2 = b1; i2 = i1; b1 = sc[e]; i1 = e; }
            else if (sc[e] > b2) { b2 = sc[e]; i2 = e; }
        }
        float w1 = 1.f / (1.f + __expf(b2 - b1));
        float w2 = 1.f - w1;
        topkw[t * 2]     = w1;
        topkw[t * 2 + 1] = w2;
        int p1 = atomicAdd(&cnt[i1], 1); elist[i1 * T_TOK + p1] = (t << 1);
        int p2 = atomicAdd(&cnt[i2], 1); elist[i2 * T_TOK + p2] = (t << 1) | 1;
    }
}

// Padded (to 128) exclusive prefix over counts -> act-buffer row bases.
__global__ void k_prefix(const int* cnt, int* base)
{
    if (threadIdx.x == 0) {
        int b = 0;
        for (int e = 0; e < E_NUM; ++e) { base[e] = b; b += ((cnt[e] + 127) >> 7) << 7; }
    }
}

// ---------------------------------------------------------------------------
// Routed gate/up GEMM. Block = 128 tokens x 128 I-cols of BOTH g and u.
// 4 waves 2x2, wave = 64x64 (4x4 of 16x16x32) for g AND u. BK=32.
// Staging: global_load_lds 16B; LDS chunk XOR-swizzle kills bank conflicts.
// ---------------------------------------------------------------------------
__global__ __launch_bounds__(256, 2)
void k_expert_gateup(const u16* xb, const u16* wgt, const u16* wut,
                     const int* elist, const int* cnt, const int* base, u16* act)
{
    int e = blockIdx.x >> 5;
    int mt = blockIdx.x & 31;
    int c = cnt[e];
    if (mt * 128 >= c) return;
    int cb = blockIdx.y;               // 0..3: 128-col block of I

    __shared__ u16 lA[128 * 32], lG[128 * 32], lU[128 * 32];

    int tid = threadIdx.x, lane = tid & 63, w = tid >> 6;
    int srow = lane >> 2, scp = lane & 3;

    const u16 *gA[2], *gG[2], *gU[2];
    u16 *dA[2], *dG[2], *dU[2];
    #pragma unroll
    for (int jj = 0; jj < 2; ++jj) {
        int call = w * 2 + jj;
        int row = call * 16 + srow;               // 0..127
        int gc = scp ^ ((row >> 1) & 3);          // swizzled global chunk
        int p = mt * 128 + row;
        int pc = p < c ? p : c - 1;
        int tok = elist[e * T_TOK + pc] >> 1;
        gA[jj] = xb + (size_t)tok * H_DIM + gc * 8;
        int colw = cb * 128 + row;
        gG[jj] = wgt + ((size_t)e * I_DIM + colw) * H_DIM + gc * 8;
        gU[jj] = wut + ((size_t)e * I_DIM + colw) * H_DIM + gc * 8;
        dA[jj] = lA + call * 512;                 // 16 rows * 32 elems
        dG[jj] = lG + call * 512;
        dU[jj] = lU + call * 512;
    }

    int wr = w >> 1, wc = w & 1;
    int quad = lane >> 4, l15 = lane & 15;
    const u16 *fA[4], *fG[4], *fU[4];
    #pragma unroll
    for (int i = 0; i < 4; ++i) {
        int r = wr * 64 + i * 16 + l15;
        fA[i] = lA + r * 32 + (quad ^ ((r >> 1) & 3)) * 8;
        int n = wc * 64 + i * 16 + l15;
        fG[i] = lG + n * 32 + (quad ^ ((n >> 1) & 3)) * 8;
        fU[i] = lU + n * 32 + (quad ^ ((n >> 1) & 3)) * 8;
    }

    floatx4 accg[4][4], accu[4][4];
    #pragma unroll
    for (int i = 0; i < 4; ++i)
        #pragma unroll
        for (int j = 0; j < 4; ++j)
            #pragma unroll
            for (int r = 0; r < 4; ++r) { accg[i][j][r] = 0.f; accu[i][j][r] = 0.f; }

    for (int s = 0; s < H_DIM / 32; ++s) {
        #pragma unroll
        for (int jj = 0; jj < 2; ++jj) {
            gld16(gA[jj], dA[jj]);
            gld16(gG[jj], dG[jj]);
            gld16(gU[jj], dU[jj]);
            gA[jj] += 32; gG[jj] += 32; gU[jj] += 32;
        }
        __syncthreads();
        short8 a[4], g[4], u[4];
        #pragma unroll
        for (int i = 0; i < 4; ++i) {
            a[i] = *(const short8*)fA[i];
            g[i] = *(const short8*)fG[i];
            u[i] = *(const short8*)fU[i];
        }
        #pragma unroll
        for (int i = 0; i < 4; ++i)
            #pragma unroll
            for (int j = 0; j < 4; ++j) {
                accg[i][j] = __builtin_amdgcn_mfma_f32_16x16x32_bf16(a[i], g[j], accg[i][j], 0, 0, 0);
                accu[i][j] = __builtin_amdgcn_mfma_f32_16x16x32_bf16(a[i], u[j], accu[i][j], 0, 0, 0);
            }
        __syncthreads();
    }

    int abase = base[e] + mt * 128;
    #pragma unroll
    for (int i = 0; i < 4; ++i)
        #pragma unroll
        for (int j = 0; j < 4; ++j)
            #pragma unroll
            for (int r = 0; r < 4; ++r) {
                int row = wr * 64 + i * 16 + quad * 4 + r;
                int col = cb * 128 + wc * 64 + j * 16 + l15;
                float gg = accg[i][j][r], uu = accu[i][j][r];
                float aa = gg / (1.f + __expf(-gg)) * uu;   // silu(g)*u
                act[(size_t)(abase + row) * I_DIM + col] = f2bf(aa);
            }
}

// ---------------------------------------------------------------------------
// Routed down GEMM. Block = 128 rows x 128 H-cols, K=512 (16 steps).
// Scatter rows (scaled) to y0/y1 slot buffers.
// ---------------------------------------------------------------------------
__global__ __launch_bounds__(256, 2)
void k_expert_down(const u16* act, const u16* wdt, const int* elist,
                   const int* cnt, const int* base, const float* topkw,
                   u16* y0, u16* y1)
{
    int e = blockIdx.x >> 5;
    int mt = blockIdx.x & 31;
    int c = cnt[e];
    if (mt * 128 >= c) return;
    int nb = blockIdx.y;               // 0..7

    __shared__ u16 lA[128 * 32], lB[128 * 32];

    int tid = threadIdx.x, lane = tid & 63, w = tid >> 6;
    int srow = lane >> 2, scp = lane & 3;

    const u16 *gA[2], *gB[2];
    u16 *dA[2], *dB[2];
    #pragma unroll
    for (int jj = 0; jj < 2; ++jj) {
        int call = w * 2 + jj;
        int row = call * 16 + srow;
        int gc = scp ^ ((row >> 1) & 3);
        gA[jj] = act + (size_t)(base[e] + mt * 128 + row) * I_DIM + gc * 8;
        gB[jj] = wdt + ((size_t)e * H_DIM + nb * 128 + row) * I_DIM + gc * 8;
        dA[jj] = lA + call * 512;
        dB[jj] = lB + call * 512;
    }

    int wr = w >> 1, wc = w & 1;
    int quad = lane >> 4, l15 = lane & 15;
    const u16 *fA[4], *fB[4];
    #pragma unroll
    for (int i = 0; i < 4; ++i) {
        int r = wr * 64 + i * 16 + l15;
        fA[i] = lA + r * 32 + (quad ^ ((r >> 1) & 3)) * 8;
        int n = wc * 64 + i * 16 + l15;
        fB[i] = lB + n * 32 + (quad ^ ((n >> 1) & 3)) * 8;
    }

    floatx4 acc[4][4];
    #pragma unroll
    for (int i = 0; i < 4; ++i)
        #pragma unroll
        for (int j = 0; j < 4; ++j)
            #pragma unroll
            for (int r = 0; r < 4; ++r) acc[i][j][r] = 0.f;

    for (int s = 0; s < I_DIM / 32; ++s) {
        #pragma unroll
        for (int jj = 0; jj < 2; ++jj) {
            gld16(gA[jj], dA[jj]);
            gld16(gB[jj], dB[jj]);
            gA[jj] += 32; gB[jj] += 32;
        }
        __syncthreads();
        short8 a[4], b[4];
        #pragma unroll
        for (int i = 0; i < 4; ++i) { a[i] = *(const short8*)fA[i]; b[i] = *(const short8*)fB[i]; }
        #pragma unroll
        for (int i = 0; i < 4; ++i)
            #pragma unroll
            for (int j = 0; j < 4; ++j)
                acc[i][j] = __builtin_amdgcn_mfma_f32_16x16x32_bf16(a[i], b[j], acc[i][j], 0, 0, 0);
        __syncthreads();
    }

    #pragma unroll
    for (int i = 0; i < 4; ++i)
        #pragma unroll
        for (int r = 0; r < 4; ++r) {
            int row = wr * 64 + i * 16 + quad * 4 + r;
            int p = mt * 128 + row;
            if (p < c) {
                int ent = elist[e * T_TOK + p];
                int t = ent >> 1, sl = ent & 1;
                float wt = topkw[t * 2 + sl];
                u16* yb = sl ? y1 : y0;
                #pragma unroll
                for (int j = 0; j < 4; ++j) {
                    int col = nb * 128 + wc * 64 + j * 16 + l15;
                    yb[(size_t)t * H_DIM + col] = f2bf(wt * acc[i][j][r]);
                }
            }
        }
}

// ---------------------------------------------------------------------------
// Shared gate/up. Block = 128 rows x 128 IS-cols (g and u). K=1024.
// ---------------------------------------------------------------------------
__global__ __launch_bounds__(256, 2)
void k_shared_gateup(const u16* xb, const u16* sgt, const u16* sut, u16* sact)
{
    int mb = blockIdx.x;               // 0..31
    int cb = blockIdx.y;               // 0..7

    __shared__ u16 lA[128 * 32], lG[128 * 32], lU[128 * 32];

    int tid = threadIdx.x, lane = tid & 63, w = tid >> 6;
    int srow = lane >> 2, scp = lane & 3;

    const u16 *gA[2], *gG[2], *gU[2];
    u16 *dA[2], *dG[2], *dU[2];
    #pragma unroll
    for (int jj = 0; jj < 2; ++jj) {
        int call = w * 2 + jj;
        int row = call * 16 + srow;
        int gc = scp ^ ((row >> 1) & 3);
        gA[jj] = xb  + (size_t)(mb * 128 + row) * H_DIM + gc * 8;
        gG[jj] = sgt + (size_t)(cb * 128 + row) * H_DIM + gc * 8;
        gU[jj] = sut + (size_t)(cb * 128 + row) * H_DIM + gc * 8;
        dA[jj] = lA + call * 512;
        dG[jj] = lG + call * 512;
        dU[jj] = lU + call * 512;
    }

    int wr = w >> 1, wc = w & 1;
    int quad = lane >> 4, l15 = lane & 15;
    const u16 *fA[4], *fG[4], *fU[4];
    #pragma unroll
    for (int i = 0; i < 4; ++i) {
        int r = wr * 64 + i * 16 + l15;
        fA[i] = lA + r * 32 + (quad ^ ((r >> 1) & 3)) * 8;
        int n = wc * 64 + i * 16 + l15;
        fG[i] = lG + n * 32 + (quad ^ ((n >> 1) & 3)) * 8;
        fU[i] = lU + n * 32 + (quad ^ ((n >> 1) & 3)) * 8;
    }

    floatx4 accg[4][4], accu[4][4];
    #pragma unroll
    for (int i = 0; i < 4; ++i)
        #pragma unroll
        for (int j = 0; j < 4; ++j)
            #pragma unroll
            for (int r = 0; r < 4; ++r) { accg[i][j][r] = 0.f; accu[i][j][r] = 0.f; }

    for (int s = 0; s < H_DIM / 32; ++s) {
        #pragma unroll
        for (int jj = 0; jj < 2; ++jj) {
            gld16(gA[jj], dA[jj]);
            gld16(gG[jj], dG[jj]);
            gld16(gU[jj], dU[jj]);
            gA[jj] += 32; gG[jj] += 32; gU[jj] += 32;
        }
        __syncthreads();
        short8 a[4], g[4], u[4];
        #pragma unroll
        for (int i = 0; i < 4; ++i) {
            a[i] = *(const short8*)fA[i];
            g[i] = *(const short8*)fG[i];
            u[i] = *(const short8*)fU[i];
        }
        #pragma unroll
        for (int i = 0; i < 4; ++i)
            #pragma unroll
            for (int j = 0; j < 4; ++j) {
                accg[i][j] = __builtin_amdgcn_mfma_f32_16x16x32_bf16(a[i], g[j], accg[i][j], 0, 0, 0);
                accu[i][j] = __builtin_amdgcn_mfma_f32_16x16x32_bf16(a[i], u[j], accu[i][j], 0, 0, 0);
            }
        __syncthreads();
    }

    #pragma unroll
    for (int i = 0; i < 4; ++i)
        #pragma unroll
        for (int j = 0; j < 4; ++j)
            #pragma unroll
            for (int r = 0; r < 4; ++r) {
                int row = mb * 128 + wr * 64 + i * 16 + quad * 4 + r;
                int col = cb * 128 + wc * 64 + j * 16 + l15;
                float gg = accg[i][j][r], uu = accu[i][j][r];
                float aa = gg / (1.f + __expf(-gg)) * uu;
                sact[(size_t)row * IS_DIM + col] = f2bf(aa);
            }
}

// ---------------------------------------------------------------------------
// Shared down + final combine: out f32 = sact@sd + y0 + y1. K=1024.
// ---------------------------------------------------------------------------
__global__ __launch_bounds__(256, 2)
void k_shared_down(const u16* sact, const u16* sdt, const u16* y0, const u16* y1,
                   float* out)
{
    int mb = blockIdx.x;               // 0..31
    int nb = blockIdx.y;               // 0..7

    __shared__ u16 lA[128 * 32], lB[128 * 32];

    int tid = threadIdx.x, lane = tid & 63, w = tid >> 6;
    int srow = lane >> 2, scp = lane & 3;

    const u16 *gA[2], *gB[2];
    u16 *dA[2], *dB[2];
    #pragma unroll
    for (int jj = 0; jj < 2; ++jj) {
        int call = w * 2 + jj;
        int row = call * 16 + srow;
        int gc = scp ^ ((row >> 1) & 3);
        gA[jj] = sact + (size_t)(mb * 128 + row) * IS_DIM + gc * 8;
        gB[jj] = sdt  + (size_t)(nb * 128 + row) * IS_DIM + gc * 8;
        dA[jj] = lA + call * 512;
        dB[jj] = lB + call * 512;
    }

    int wr = w >> 1, wc = w & 1;
    int quad = lane >> 4, l15 = lane & 15;
    const u16 *fA[4], *fB[4];
    #pragma unroll
    for (int i = 0; i < 4; ++i) {
        int r = wr * 64 + i * 16 + l15;
        fA[i] = lA + r * 32 + (quad ^ ((r >> 1) & 3)) * 8;
        int n = wc * 64 + i * 16 + l15;
        fB[i] = lB + n * 32 + (quad ^ ((n >> 1) & 3)) * 8;
    }

    floatx4 acc[4][4];
    #pragma unroll
    for (int i = 0; i < 4; ++i)
        #pragma unroll
        for (int j = 0; j < 4; ++j)
            #pragma unroll
            for (int r = 0; r < 4; ++r) acc[i][j][r] = 0.f;

    for (int s = 0; s < IS_DIM / 32; ++s) {
        #pragma unroll
        for (int jj = 0; jj < 2; ++jj) {
            gld16(gA[jj], dA[jj]);
            gld16(gB[jj], dB[jj]);
            gA[jj] += 32; gB[jj] += 32;
        }
        __syncthreads();
        short8 a[4], b[4];
        #pragma unroll
        for (int i = 0; i < 4; ++i) { a[i] = *(const short8*)fA[i]; b[i] = *(const short8*)fB[i]; }
        #pragma unroll
        for (int i = 0; i < 4; ++i)
            #pragma unroll
            for (int j = 0; j < 4; ++j)
                acc[i][j] = __builtin_amdgcn_mfma_f32_16x16x32_bf16(a[i], b[j], acc[i][j], 0, 0, 0);
        __syncthreads();
    }

    #pragma unroll
    for (int i = 0; i < 4; ++i)
        #pragma unroll
        for (int j = 0; j < 4; ++j)
            #pragma unroll
            for (int r = 0; r < 4; ++r) {
                int row = mb * 128 + wr * 64 + i * 16 + quad * 4 + r;
                int col = nb * 128 + wc * 64 + j * 16 + l15;
                float v = acc[i][j][r] + bf2f(y0[(size_t)row * H_DIM + col])
                                       + bf2f(y1[(size_t)row * H_DIM + col]);
                out[(size_t)row * H_DIM + col] = v;
            }
}

// ---------------------------------------------------------------------------
extern "C" void kernel_launch(void* const* d_in, const int* in_sizes, int n_in,
                              void* d_out, int out_size, void* d_ws, size_t ws_size,
                              hipStream_t stream)
{
    const float* x  = (const float*)d_in[0];
    const float* rw = (const float*)d_in[1];
    const float* wg = (const float*)d_in[2];
    const float* wu = (const float*)d_in[3];
    const float* wd = (const float*)d_in[4];
    const float* sg = (const float*)d_in[5];
    const float* su = (const float*)d_in[6];
    const float* sd = (const float*)d_in[7];
    float* out = (float*)d_out;

    char* ws = (char*)d_ws;
    const size_t MB = 1024ull * 1024ull;
    u16* wgt  = (u16*)(ws);            // [E][I][H] bf16  16 MB
    u16* wut  = (u16*)(ws + 16 * MB);  // [E][I][H]       16 MB
    u16* wdt  = (u16*)(ws + 32 * MB);  // [E][H][I]       16 MB
    u16* sgt  = (u16*)(ws + 48 * MB);  // [IS][H]          2 MB
    u16* sut  = (u16*)(ws + 50 * MB);  // [IS][H]          2 MB
    u16* sdt  = (u16*)(ws + 52 * MB);  // [H][IS]          2 MB
    u16* xb   = (u16*)(ws + 54 * MB);  // [T][H] bf16      8 MB
    u16* act  = (u16*)(ws + 62 * MB);  // [<=10240][I]    10 MB (128-padded rows)
    u16* sact = (u16*)(ws + 72 * MB);  // [T][IS]          8 MB
    u16* y0   = (u16*)(ws + 80 * MB);  // [T][H] slot0     8 MB
    u16* y1   = (u16*)(ws + 88 * MB);  // [T][H] slot1     8 MB
    float* topkw = (float*)(ws + 96 * MB);          // [T][2]
    int* elist   = (int*)(ws + 96 * MB + 64 * 1024);// [E][T]
    int* cnt     = (int*)(ws + 97 * MB);            // [E]
    int* base    = (int*)(ws + 97 * MB + 256);      // [E]

    hipMemsetAsync(cnt, 0, E_NUM * sizeof(int), stream);
    k_transpose<<<6912, 256, 0, stream>>>(wg, wu, wd, sg, su, sd,
                                          wgt, wut, wdt, sgt, sut, sdt);
    k_xconv<<<T_TOK * H_DIM / 4 / 256, 256, 0, stream>>>(x, xb);
    k_router<<<T_TOK / 4, 256, 0, stream>>>(x, rw, topkw, elist, cnt);
    k_prefix<<<1, 64, 0, stream>>>(cnt, base);
    k_expert_gateup<<<dim3(E_NUM * 32, I_DIM / 128), 256, 0, stream>>>(
        xb, wgt, wut, elist, cnt, base, act);
    k_expert_down<<<dim3(E_NUM * 32, H_DIM / 128), 256, 0, stream>>>(
        act, wdt, elist, cnt, base, topkw, y0, y1);
    k_shared_gateup<<<dim3(T_TOK / 128, IS_DIM / 128), 256, 0, stream>>>(
        xb, sgt, sut, sact);
    k_shared_down<<<dim3(T_TOK / 128, H_DIM / 128), 256, 0, stream>>>(
        sact, sdt, y0, y1, out);
}

// Round 5
// 397.878 us; speedup vs baseline: 2.9376x; 1.4347x over previous
//
#include <hip/hip_runtime.h>
#include <hip/hip_bf16.h>
#include <math.h>

// SigmaMoE: T=4096 tokens, H=1024, I=512, E=16 experts, top-2, shared IS=1024.
// Inputs/outputs FLOAT32; internal GEMMs bf16 MFMA 16x16x32, 128x128 tiles,
// global_load_lds width-16 staging, XOR-swizzled LDS (0 bank conflicts).
// R5: device-built compact tile lists (no structured early-exit -> XCD balance),
// routed+shared fused into one gate/up dispatch and one down dispatch.
#define H_DIM 1024
#define I_DIM 512
#define E_NUM 16
#define T_TOK 4096
#define IS_DIM 1024
#define MAX_GU 576   // <= 80 routed m-tiles*4 + 32 shared m-tiles*8
#define MAX_DN 896   // <= 80*8 + 32*8

typedef unsigned short u16;
typedef __attribute__((ext_vector_type(8))) short short8;   // 8 x bf16 frag (16B)
typedef __attribute__((ext_vector_type(4))) float floatx4;  // 16x16 acc

__device__ __forceinline__ float bf2f(u16 u) {
    union { unsigned int u; float f; } c; c.u = ((unsigned int)u) << 16; return c.f;
}
__device__ __forceinline__ u16 f2bf(float f) {
    union { float f; unsigned int u; } c; c.f = f;
    unsigned int r = (c.u + 0x7fffu + ((c.u >> 16) & 1u)) >> 16;
    return (u16)r;
}
// async global->LDS, 16B/lane; LDS dest = wave-uniform base + lane*16.
__device__ __forceinline__ void gld16(const u16* g, u16* l) {
    __builtin_amdgcn_global_load_lds(
        (const __attribute__((address_space(1))) unsigned int*)g,
        (__attribute__((address_space(3))) unsigned int*)l, 16, 0, 0);
}

// ---------------------------------------------------------------------------
// Weight convert+transpose: f32 K-major -> bf16 N-major. (unchanged, works)
// ---------------------------------------------------------------------------
__global__ __launch_bounds__(256)
void k_transpose(const float* wg, const float* wu, const float* wd,
                 const float* sg, const float* su, const float* sd,
                 u16* wgt, u16* wut, u16* wdt, u16* sgt, u16* sut, u16* sdt)
{
    int bx = blockIdx.x;
    const float* src; u16* dst; int R, C, local;
    if (bx < 2048)      { src = wg; dst = wgt; R = 1024; C = 512;  local = bx; }
    else if (bx < 4096) { src = wu; dst = wut; R = 1024; C = 512;  local = bx - 2048; }
    else if (bx < 6144) { src = wd; dst = wdt; R = 512;  C = 1024; local = bx - 4096; }
    else if (bx < 6400) { src = sg; dst = sgt; R = 1024; C = 1024; local = bx - 6144; }
    else if (bx < 6656) { src = su; dst = sut; R = 1024; C = 1024; local = bx - 6400; }
    else                { src = sd; dst = sdt; R = 1024; C = 1024; local = bx - 6656; }
    int tpm = (R >> 6) * (C >> 6);
    int mat = local / tpm;
    int tl_ = local - mat * tpm;
    int tcn = C >> 6;
    int tr = tl_ / tcn, tc = tl_ - (tl_ / tcn) * tcn;
    src += (size_t)mat * R * C;
    dst += (size_t)mat * R * C;

    __shared__ u16 tile[64][65];
    int t = threadIdx.x;
    int r0 = t >> 2, c0 = (t & 3) * 16;
    const float* sp = src + (size_t)(tr * 64 + r0) * C + tc * 64 + c0;
    #pragma unroll
    for (int j = 0; j < 16; j += 4) {
        float4 v = *(const float4*)(sp + j);
        tile[r0][c0 + j + 0] = f2bf(v.x);
        tile[r0][c0 + j + 1] = f2bf(v.y);
        tile[r0][c0 + j + 2] = f2bf(v.z);
        tile[r0][c0 + j + 3] = f2bf(v.w);
    }
    __syncthreads();
    int cW = t >> 2, rW = (t & 3) * 16;
    u16 tmp[16];
    #pragma unroll
    for (int j = 0; j < 16; ++j) tmp[j] = tile[rW + j][cW];
    u16* dp = dst + (size_t)(tc * 64 + cW) * R + tr * 64 + rW;
    *(uint4*)(dp)     = *(const uint4*)(tmp);
    *(uint4*)(dp + 8) = *(const uint4*)(tmp + 8);
}

// f32 -> bf16 copy of x.
__global__ __launch_bounds__(256)
void k_xconv(const float* x, u16* xb)
{
    int i = blockIdx.x * 256 + threadIdx.x;
    float4 v = ((const float4*)x)[i];
    u16 o[4] = { f2bf(v.x), f2bf(v.y), f2bf(v.z), f2bf(v.w) };
    ((uint2*)xb)[i] = *(const uint2*)o;
}

// ---------------------------------------------------------------------------
// Router (unchanged, works).
// ---------------------------------------------------------------------------
__global__ __launch_bounds__(256)
void k_router(const float* x, const float* rw, float* topkw, int* elist, int* cnt)
{
    int lane = threadIdx.x & 63;
    int wv = threadIdx.x >> 6;
    int t = blockIdx.x * 4 + wv;
    const float* xr = x + (size_t)t * H_DIM;
    float xv[16];
    #pragma unroll
    for (int j = 0; j < 16; ++j) xv[j] = xr[j * 64 + lane];
    float sc[E_NUM];
    #pragma unroll
    for (int e = 0; e < E_NUM; ++e) {
        const float* rr = rw + e * H_DIM;
        float s = 0.f;
        #pragma unroll
        for (int j = 0; j < 16; ++j) s += xv[j] * rr[j * 64 + lane];
        #pragma unroll
        for (int off = 32; off > 0; off >>= 1) s += __shfl_xor(s, off, 64);
        sc[e] = s;
    }
    if (lane == 0) {
        float b1 = -1e30f, b2 = -1e30f; int i1 = 0, i2 = 0;
        #pragma unroll
        for (int e = 0; e < E_NUM; ++e) {
            if (sc[e] > b1) { b2 = b1; i2 = i1; b1 = sc[e]; i1 = e; }
            else if (sc[e] > b2) { b2 = sc[e]; i2 = e; }
        }
        float w1 = 1.f / (1.f + __expf(b2 - b1));
        float w2 = 1.f - w1;
        topkw[t * 2]     = w1;
        topkw[t * 2 + 1] = w2;
        int p1 = atomicAdd(&cnt[i1], 1); elist[i1 * T_TOK + p1] = (t << 1);
        int p2 = atomicAdd(&cnt[i2], 1); elist[i2 * T_TOK + p2] = (t << 1) | 1;
    }
}

// ---------------------------------------------------------------------------
// Prefix + tile-list builder. desc = kind<<31 | e<<16 | mt<<8 | cb.
// Routed tiles first (mt-major, cb inner), then shared (kind=1, e=0).
// ---------------------------------------------------------------------------
__global__ void k_prefix(const int* cnt, int* base,
                         int* gu_desc, int* gu_count, int* dn_desc, int* dn_count)
{
    if (threadIdx.x == 0) {
        int b = 0, ngu = 0, ndn = 0;
        for (int e = 0; e < E_NUM; ++e) {
            base[e] = b;
            int mts = (cnt[e] + 127) >> 7;
            b += mts << 7;
            for (int mt = 0; mt < mts; ++mt) {
                for (int cb = 0; cb < 4; ++cb) gu_desc[ngu++] = (e << 16) | (mt << 8) | cb;
                for (int nb = 0; nb < 8; ++nb) dn_desc[ndn++] = (e << 16) | (mt << 8) | nb;
            }
        }
        for (int mt = 0; mt < T_TOK / 128; ++mt) {
            for (int cb = 0; cb < 8; ++cb) gu_desc[ngu++] = (1 << 31) | (mt << 8) | cb;
            for (int nb = 0; nb < 8; ++nb) dn_desc[ndn++] = (1 << 31) | (mt << 8) | nb;
        }
        *gu_count = ngu; *dn_count = ndn;
    }
}

// ---------------------------------------------------------------------------
// Fused gate/up GEMM (routed + shared). Block = 128 rows x 128 cols of both
// g and u, K=1024. 4 waves 2x2, wave 64x64 (4x4 MFMA) per g and u.
// ---------------------------------------------------------------------------
__global__ __launch_bounds__(256, 2)
void k_gateup(const u16* xb, const u16* wgt, const u16* wut,
              const u16* sgt, const u16* sut,
              const int* elist, const int* cnt, const int* base,
              const int* gu_desc, const int* gu_count,
              u16* act, u16* sact)
{
    int bi = blockIdx.x;
    if (bi >= *gu_count) return;
    int d = gu_desc[bi];
    int kind = ((unsigned)d) >> 31;          // 0 routed, 1 shared
    int e = (d >> 16) & 15, mt = (d >> 8) & 255, cb = d & 7;

    __shared__ u16 lA[128 * 32], lG[128 * 32], lU[128 * 32];
    int tid = threadIdx.x, lane = tid & 63, w = tid >> 6;
    int srow = lane >> 2, scp = lane & 3;

    const u16* gb = kind ? sgt : (wgt + (size_t)e * I_DIM * H_DIM);
    const u16* ub = kind ? sut : (wut + (size_t)e * I_DIM * H_DIM);
    int c = cnt[e];

    const u16 *gA[2], *gG[2], *gU[2];
    u16 *dA[2], *dG[2], *dU[2];
    #pragma unroll
    for (int jj = 0; jj < 2; ++jj) {
        int call = w * 2 + jj;
        int row = call * 16 + srow;               // 0..127
        int gc = scp ^ ((row >> 1) & 3);
        int tok;
        if (kind) tok = mt * 128 + row;
        else {
            int p = mt * 128 + row;
            int pc = p < c ? p : c - 1;
            tok = elist[e * T_TOK + pc] >> 1;
        }
        gA[jj] = xb + (size_t)tok * H_DIM + gc * 8;
        gG[jj] = gb + (size_t)(cb * 128 + row) * H_DIM + gc * 8;
        gU[jj] = ub + (size_t)(cb * 128 + row) * H_DIM + gc * 8;
        dA[jj] = lA + call * 512;
        dG[jj] = lG + call * 512;
        dU[jj] = lU + call * 512;
    }

    int wr = w >> 1, wc = w & 1;
    int quad = lane >> 4, l15 = lane & 15;
    const u16 *fA[4], *fG[4], *fU[4];
    #pragma unroll
    for (int i = 0; i < 4; ++i) {
        int r = wr * 64 + i * 16 + l15;
        fA[i] = lA + r * 32 + (quad ^ ((r >> 1) & 3)) * 8;
        int n = wc * 64 + i * 16 + l15;
        fG[i] = lG + n * 32 + (quad ^ ((n >> 1) & 3)) * 8;
        fU[i] = lU + n * 32 + (quad ^ ((n >> 1) & 3)) * 8;
    }

    floatx4 accg[4][4], accu[4][4];
    #pragma unroll
    for (int i = 0; i < 4; ++i)
        #pragma unroll
        for (int j = 0; j < 4; ++j)
            #pragma unroll
            for (int r = 0; r < 4; ++r) { accg[i][j][r] = 0.f; accu[i][j][r] = 0.f; }

    for (int s = 0; s < H_DIM / 32; ++s) {
        #pragma unroll
        for (int jj = 0; jj < 2; ++jj) {
            gld16(gA[jj], dA[jj]);
            gld16(gG[jj], dG[jj]);
            gld16(gU[jj], dU[jj]);
            gA[jj] += 32; gG[jj] += 32; gU[jj] += 32;
        }
        __syncthreads();
        short8 a[4], g[4], u[4];
        #pragma unroll
        for (int i = 0; i < 4; ++i) {
            a[i] = *(const short8*)fA[i];
            g[i] = *(const short8*)fG[i];
            u[i] = *(const short8*)fU[i];
        }
        #pragma unroll
        for (int i = 0; i < 4; ++i)
            #pragma unroll
            for (int j = 0; j < 4; ++j) {
                accg[i][j] = __builtin_amdgcn_mfma_f32_16x16x32_bf16(a[i], g[j], accg[i][j], 0, 0, 0);
                accu[i][j] = __builtin_amdgcn_mfma_f32_16x16x32_bf16(a[i], u[j], accu[i][j], 0, 0, 0);
            }
        __syncthreads();
    }

    u16* obase = kind ? (sact + (size_t)(mt * 128) * IS_DIM)
                      : (act + (size_t)(base[e] + mt * 128) * I_DIM);
    int old = kind ? IS_DIM : I_DIM;
    #pragma unroll
    for (int i = 0; i < 4; ++i)
        #pragma unroll
        for (int j = 0; j < 4; ++j)
            #pragma unroll
            for (int r = 0; r < 4; ++r) {
                int row = wr * 64 + i * 16 + quad * 4 + r;
                int col = cb * 128 + wc * 64 + j * 16 + l15;
                float gg = accg[i][j][r], uu = accu[i][j][r];
                float aa = gg / (1.f + __expf(-gg)) * uu;   // silu(g)*u
                obase[(size_t)row * old + col] = f2bf(aa);
            }
}

// ---------------------------------------------------------------------------
// Fused down GEMM (routed K=512 -> y0/y1 scaled scatter; shared K=1024 -> out).
// ---------------------------------------------------------------------------
__global__ __launch_bounds__(256, 2)
void k_down(const u16* act, const u16* sact, const u16* wdt, const u16* sdt,
            const int* elist, const int* cnt, const int* base, const float* topkw,
            const int* dn_desc, const int* dn_count,
            u16* y0, u16* y1, float* out)
{
    int bi = blockIdx.x;
    if (bi >= *dn_count) return;
    int d = dn_desc[bi];
    int kind = ((unsigned)d) >> 31;
    int e = (d >> 16) & 15, mt = (d >> 8) & 255, nb = d & 7;

    __shared__ u16 lA[128 * 32], lB[128 * 32];
    int tid = threadIdx.x, lane = tid & 63, w = tid >> 6;
    int srow = lane >> 2, scp = lane & 3;

    int K = kind ? IS_DIM : I_DIM;
    const u16* ab = kind ? (sact + (size_t)(mt * 128) * IS_DIM)
                         : (act + (size_t)(base[e] + mt * 128) * I_DIM);
    const u16* bb = kind ? (sdt + (size_t)(nb * 128) * IS_DIM)
                         : (wdt + ((size_t)e * H_DIM + nb * 128) * I_DIM);
    int c = cnt[e];

    const u16 *gA[2], *gB[2];
    u16 *dA[2], *dB[2];
    #pragma unroll
    for (int jj = 0; jj < 2; ++jj) {
        int call = w * 2 + jj;
        int row = call * 16 + srow;
        int gc = scp ^ ((row >> 1) & 3);
        gA[jj] = ab + (size_t)row * K + gc * 8;
        gB[jj] = bb + (size_t)row * K + gc * 8;
        dA[jj] = lA + call * 512;
        dB[jj] = lB + call * 512;
    }

    int wr = w >> 1, wc = w & 1;
    int quad = lane >> 4, l15 = lane & 15;
    const u16 *fA[4], *fB[4];
    #pragma unroll
    for (int i = 0; i < 4; ++i) {
        int r = wr * 64 + i * 16 + l15;
        fA[i] = lA + r * 32 + (quad ^ ((r >> 1) & 3)) * 8;
        int n = wc * 64 + i * 16 + l15;
        fB[i] = lB + n * 32 + (quad ^ ((n >> 1) & 3)) * 8;
    }

    floatx4 acc[4][4];
    #pragma unroll
    for (int i = 0; i < 4; ++i)
        #pragma unroll
        for (int j = 0; j < 4; ++j)
            #pragma unroll
            for (int r = 0; r < 4; ++r) acc[i][j][r] = 0.f;

    int steps = K >> 5;
    for (int s = 0; s < steps; ++s) {
        #pragma unroll
        for (int jj = 0; jj < 2; ++jj) {
            gld16(gA[jj], dA[jj]);
            gld16(gB[jj], dB[jj]);
            gA[jj] += 32; gB[jj] += 32;
        }
        __syncthreads();
        short8 a[4], b[4];
        #pragma unroll
        for (int i = 0; i < 4; ++i) { a[i] = *(const short8*)fA[i]; b[i] = *(const short8*)fB[i]; }
        #pragma unroll
        for (int i = 0; i < 4; ++i)
            #pragma unroll
            for (int j = 0; j < 4; ++j)
                acc[i][j] = __builtin_amdgcn_mfma_f32_16x16x32_bf16(a[i], b[j], acc[i][j], 0, 0, 0);
        __syncthreads();
    }

    if (kind) {
        #pragma unroll
        for (int i = 0; i < 4; ++i)
            #pragma unroll
            for (int j = 0; j < 4; ++j)
                #pragma unroll
                for (int r = 0; r < 4; ++r) {
                    int row = mt * 128 + wr * 64 + i * 16 + quad * 4 + r;
                    int col = nb * 128 + wc * 64 + j * 16 + l15;
                    out[(size_t)row * H_DIM + col] = acc[i][j][r];
                }
    } else {
        #pragma unroll
        for (int i = 0; i < 4; ++i)
            #pragma unroll
            for (int r = 0; r < 4; ++r) {
                int row = wr * 64 + i * 16 + quad * 4 + r;
                int p = mt * 128 + row;
                if (p < c) {
                    int ent = elist[e * T_TOK + p];
                    int t = ent >> 1, sl = ent & 1;
                    float wt = topkw[t * 2 + sl];
                    u16* yb = sl ? y1 : y0;
                    #pragma unroll
                    for (int j = 0; j < 4; ++j) {
                        int col = nb * 128 + wc * 64 + j * 16 + l15;
                        yb[(size_t)t * H_DIM + col] = f2bf(wt * acc[i][j][r]);
                    }
                }
            }
    }
}

// Final combine: out += y0 + y1 (out already holds shared-expert result).
__global__ __launch_bounds__(256)
void k_final(float* out, const u16* y0, const u16* y1)
{
    int i = blockIdx.x * 256 + threadIdx.x;    // float4 / 4-elem granularity
    float4 o = ((const float4*)out)[i];
    uint2 a = ((const uint2*)y0)[i];
    uint2 b = ((const uint2*)y1)[i];
    const u16* pa = (const u16*)&a;
    const u16* pb = (const u16*)&b;
    o.x += bf2f(pa[0]) + bf2f(pb[0]);
    o.y += bf2f(pa[1]) + bf2f(pb[1]);
    o.z += bf2f(pa[2]) + bf2f(pb[2]);
    o.w += bf2f(pa[3]) + bf2f(pb[3]);
    ((float4*)out)[i] = o;
}

// ---------------------------------------------------------------------------
extern "C" void kernel_launch(void* const* d_in, const int* in_sizes, int n_in,
                              void* d_out, int out_size, void* d_ws, size_t ws_size,
                              hipStream_t stream)
{
    const float* x  = (const float*)d_in[0];
    const float* rw = (const float*)d_in[1];
    const float* wg = (const float*)d_in[2];
    const float* wu = (const float*)d_in[3];
    const float* wd = (const float*)d_in[4];
    const float* sg = (const float*)d_in[5];
    const float* su = (const float*)d_in[6];
    const float* sd = (const float*)d_in[7];
    float* out = (float*)d_out;

    char* ws = (char*)d_ws;
    const size_t MB = 1024ull * 1024ull;
    u16* wgt  = (u16*)(ws);            // [E][I][H] bf16  16 MB
    u16* wut  = (u16*)(ws + 16 * MB);  // [E][I][H]       16 MB
    u16* wdt  = (u16*)(ws + 32 * MB);  // [E][H][I]       16 MB
    u16* sgt  = (u16*)(ws + 48 * MB);  // [IS][H]          2 MB
    u16* sut  = (u16*)(ws + 50 * MB);  // [IS][H]          2 MB
    u16* sdt  = (u16*)(ws + 52 * MB);  // [H][IS]          2 MB
    u16* xb   = (u16*)(ws + 54 * MB);  // [T][H] bf16      8 MB
    u16* act  = (u16*)(ws + 62 * MB);  // [<=10240][I]    10 MB (128-padded rows)
    u16* sact = (u16*)(ws + 72 * MB);  // [T][IS]          8 MB
    u16* y0   = (u16*)(ws + 80 * MB);  // [T][H] slot0     8 MB
    u16* y1   = (u16*)(ws + 88 * MB);  // [T][H] slot1     8 MB
    float* topkw  = (float*)(ws + 96 * MB);            // [T][2]
    int* elist    = (int*)(ws + 96 * MB + 64 * 1024);  // [E][T]
    int* cnt      = (int*)(ws + 97 * MB);              // [E]
    int* base     = (int*)(ws + 97 * MB + 256);        // [E]
    int* gu_count = (int*)(ws + 97 * MB + 512);
    int* dn_count = (int*)(ws + 97 * MB + 516);
    int* gu_desc  = (int*)(ws + 97 * MB + 1024);       // <=576 ints
    int* dn_desc  = (int*)(ws + 97 * MB + 8192);       // <=896 ints

    hipMemsetAsync(cnt, 0, E_NUM * sizeof(int), stream);
    k_transpose<<<6912, 256, 0, stream>>>(wg, wu, wd, sg, su, sd,
                                          wgt, wut, wdt, sgt, sut, sdt);
    k_xconv<<<T_TOK * H_DIM / 4 / 256, 256, 0, stream>>>(x, xb);
    k_router<<<T_TOK / 4, 256, 0, stream>>>(x, rw, topkw, elist, cnt);
    k_prefix<<<1, 64, 0, stream>>>(cnt, base, gu_desc, gu_count, dn_desc, dn_count);
    k_gateup<<<MAX_GU, 256, 0, stream>>>(xb, wgt, wut, sgt, sut,
                                         elist, cnt, base, gu_desc, gu_count,
                                         act, sact);
    k_down<<<MAX_DN, 256, 0, stream>>>(act, sact, wdt, sdt,
                                       elist, cnt, base, topkw,
                                       dn_desc, dn_count, y0, y1, out);
    k_final<<<T_TOK * H_DIM / 4 / 256, 256, 0, stream>>>(out, y0, y1);
}

// Round 6
// 383.944 us; speedup vs baseline: 3.0442x; 1.0363x over previous
//
#include <hip/hip_runtime.h>
#include <hip/hip_bf16.h>
#include <math.h>

// SigmaMoE: T=4096 tokens, H=1024, I=512, E=16 experts, top-2, shared IS=1024.
// Inputs/outputs FLOAT32; internal GEMMs bf16 MFMA 16x16x32, 128x64 tiles,
// global_load_lds width-16 staging, XOR-swizzled LDS (0 bank conflicts).
// R6: router batched-butterfly reduction (ILP over experts); 64-col tiles for
// 4-7 blocks/CU co-residency; parallel k_prefix, shared (heavy) tiles first.
#define H_DIM 1024
#define I_DIM 512
#define E_NUM 16
#define T_TOK 4096
#define IS_DIM 1024
#define MAX_GU 1152   // 32*16 shared + <=80 routed m-tiles * 8
#define MAX_DN 1792   // 32*16 shared + <=80 routed m-tiles * 16

typedef unsigned short u16;
typedef __attribute__((ext_vector_type(8))) short short8;   // 8 x bf16 frag (16B)
typedef __attribute__((ext_vector_type(4))) float floatx4;  // 16x16 acc

__device__ __forceinline__ float bf2f(u16 u) {
    union { unsigned int u; float f; } c; c.u = ((unsigned int)u) << 16; return c.f;
}
__device__ __forceinline__ u16 f2bf(float f) {
    union { float f; unsigned int u; } c; c.f = f;
    unsigned int r = (c.u + 0x7fffu + ((c.u >> 16) & 1u)) >> 16;
    return (u16)r;
}
// async global->LDS, 16B/lane; LDS dest = wave-uniform base + lane*16.
__device__ __forceinline__ void gld16(const u16* g, u16* l) {
    __builtin_amdgcn_global_load_lds(
        (const __attribute__((address_space(1))) unsigned int*)g,
        (__attribute__((address_space(3))) unsigned int*)l, 16, 0, 0);
}

// ---------------------------------------------------------------------------
// Weight convert+transpose: f32 K-major -> bf16 N-major. (unchanged, works)
// ---------------------------------------------------------------------------
__global__ __launch_bounds__(256)
void k_transpose(const float* wg, const float* wu, const float* wd,
                 const float* sg, const float* su, const float* sd,
                 u16* wgt, u16* wut, u16* wdt, u16* sgt, u16* sut, u16* sdt)
{
    int bx = blockIdx.x;
    const float* src; u16* dst; int R, C, local;
    if (bx < 2048)      { src = wg; dst = wgt; R = 1024; C = 512;  local = bx; }
    else if (bx < 4096) { src = wu; dst = wut; R = 1024; C = 512;  local = bx - 2048; }
    else if (bx < 6144) { src = wd; dst = wdt; R = 512;  C = 1024; local = bx - 4096; }
    else if (bx < 6400) { src = sg; dst = sgt; R = 1024; C = 1024; local = bx - 6144; }
    else if (bx < 6656) { src = su; dst = sut; R = 1024; C = 1024; local = bx - 6400; }
    else                { src = sd; dst = sdt; R = 1024; C = 1024; local = bx - 6656; }
    int tpm = (R >> 6) * (C >> 6);
    int mat = local / tpm;
    int tl_ = local - mat * tpm;
    int tcn = C >> 6;
    int tr = tl_ / tcn, tc = tl_ - (tl_ / tcn) * tcn;
    src += (size_t)mat * R * C;
    dst += (size_t)mat * R * C;

    __shared__ u16 tile[64][65];
    int t = threadIdx.x;
    int r0 = t >> 2, c0 = (t & 3) * 16;
    const float* sp = src + (size_t)(tr * 64 + r0) * C + tc * 64 + c0;
    #pragma unroll
    for (int j = 0; j < 16; j += 4) {
        float4 v = *(const float4*)(sp + j);
        tile[r0][c0 + j + 0] = f2bf(v.x);
        tile[r0][c0 + j + 1] = f2bf(v.y);
        tile[r0][c0 + j + 2] = f2bf(v.z);
        tile[r0][c0 + j + 3] = f2bf(v.w);
    }
    __syncthreads();
    int cW = t >> 2, rW = (t & 3) * 16;
    u16 tmp[16];
    #pragma unroll
    for (int j = 0; j < 16; ++j) tmp[j] = tile[rW + j][cW];
    u16* dp = dst + (size_t)(tc * 64 + cW) * R + tr * 64 + rW;
    *(uint4*)(dp)     = *(const uint4*)(tmp);
    *(uint4*)(dp + 8) = *(const uint4*)(tmp + 8);
}

// f32 -> bf16 copy of x.
__global__ __launch_bounds__(256)
void k_xconv(const float* x, u16* xb)
{
    int i = blockIdx.x * 256 + threadIdx.x;
    float4 v = ((const float4*)x)[i];
    u16 o[4] = { f2bf(v.x), f2bf(v.y), f2bf(v.z), f2bf(v.w) };
    ((uint2*)xb)[i] = *(const uint2*)o;
}

// ---------------------------------------------------------------------------
// Router. Batched butterfly: expert loop INSIDE each shuffle level -> ILP=16
// hides the ~120cyc DS latency (R5 had it per-expert serial: 108us).
// ---------------------------------------------------------------------------
__global__ __launch_bounds__(256)
void k_router(const float* x, const float* rw, float* topkw, int* elist, int* cnt)
{
    int lane = threadIdx.x & 63;
    int wv = threadIdx.x >> 6;
    int t = blockIdx.x * 4 + wv;
    const float* xr = x + (size_t)t * H_DIM;
    float xv[16];
    #pragma unroll
    for (int j = 0; j < 16; ++j) xv[j] = xr[j * 64 + lane];
    float sc[E_NUM];
    #pragma unroll
    for (int e = 0; e < E_NUM; ++e) sc[e] = 0.f;
    #pragma unroll
    for (int e = 0; e < E_NUM; ++e) {
        const float* rr = rw + e * H_DIM;
        #pragma unroll
        for (int j = 0; j < 16; ++j) sc[e] += xv[j] * rr[j * 64 + lane];
    }
    // batched 64-lane butterfly: 16 independent shuffles per level
    #pragma unroll
    for (int off = 32; off > 0; off >>= 1) {
        float tmp[E_NUM];
        #pragma unroll
        for (int e = 0; e < E_NUM; ++e) tmp[e] = __shfl_xor(sc[e], off, 64);
        #pragma unroll
        for (int e = 0; e < E_NUM; ++e) sc[e] += tmp[e];
    }
    if (lane == 0) {
        float b1 = -1e30f, b2 = -1e30f; int i1 = 0, i2 = 0;
        #pragma unroll
        for (int e = 0; e < E_NUM; ++e) {
            if (sc[e] > b1) { b2 = b1; i2 = i1; b1 = sc[e]; i1 = e; }
            else if (sc[e] > b2) { b2 = sc[e]; i2 = e; }
        }
        float w1 = 1.f / (1.f + __expf(b2 - b1));
        float w2 = 1.f - w1;
        topkw[t * 2]     = w1;
        topkw[t * 2 + 1] = w2;
        int p1 = atomicAdd(&cnt[i1], 1); elist[i1 * T_TOK + p1] = (t << 1);
        int p2 = atomicAdd(&cnt[i2], 1); elist[i2 * T_TOK + p2] = (t << 1) | 1;
    }
}

// ---------------------------------------------------------------------------
// Prefix + tile-list builder (parallel, 1 block of 64).
// desc = kind<<31 | e<<16 | mt<<8 | cb.  Shared (heavy) tiles first.
// ---------------------------------------------------------------------------
__global__ void k_prefix(const int* cnt, int* base,
                         int* gu_desc, int* gu_count, int* dn_desc, int* dn_count)
{
    __shared__ int mts_s[E_NUM], moff_s[E_NUM];
    int lane = threadIdx.x;  // 64 threads
    if (lane == 0) {
        int b = 0, mo = 0;
        for (int e = 0; e < E_NUM; ++e) {
            int mts = (cnt[e] + 127) >> 7;
            base[e] = b; b += mts << 7;
            mts_s[e] = mts; moff_s[e] = mo; mo += mts;
        }
        *gu_count = 512 + mo * 8;
        *dn_count = 512 + mo * 16;
    }
    __syncthreads();
    // shared tiles: 32 mt x 16 cb for both gu and dn
    for (int i = lane; i < 512; i += 64) {
        int mt = i >> 4, cb = i & 15;
        int d = (1 << 31) | (mt << 8) | cb;
        gu_desc[i] = d;
        dn_desc[i] = d;
    }
    if (lane < E_NUM) {
        int e = lane, mts = mts_s[e], mo = moff_s[e];
        for (int mt = 0; mt < mts; ++mt) {
            #pragma unroll
            for (int cb = 0; cb < 8; ++cb)
                gu_desc[512 + (mo + mt) * 8 + cb] = (e << 16) | (mt << 8) | cb;
            #pragma unroll
            for (int nb = 0; nb < 16; ++nb)
                dn_desc[512 + (mo + mt) * 16 + nb] = (e << 16) | (mt << 8) | nb;
        }
    }
}

// ---------------------------------------------------------------------------
// Fused gate/up GEMM (routed + shared). Block = 128 rows x 64 cols of both
// g and u, K=1024. 4 waves 2x2: wave = 64 rows x 32 cols per matrix.
// Routed: cb 0..7 (I=512); shared: cb 0..15 (IS=1024).
// ---------------------------------------------------------------------------
__global__ __launch_bounds__(256, 2)
void k_gateup(const u16* xb, const u16* wgt, const u16* wut,
              const u16* sgt, const u16* sut,
              const int* elist, const int* cnt, const int* base,
              const int* gu_desc, const int* gu_count,
              u16* act, u16* sact)
{
    int bi = blockIdx.x;
    if (bi >= *gu_count) return;
    int d = gu_desc[bi];
    int kind = ((unsigned)d) >> 31;          // 0 routed, 1 shared
    int e = (d >> 16) & 15, mt = (d >> 8) & 255, cb = d & 255;

    __shared__ u16 lA[128 * 32], lG[64 * 32], lU[64 * 32];
    int tid = threadIdx.x, lane = tid & 63, w = tid >> 6;
    int srow = lane >> 2, scp = lane & 3;

    const u16* gb = kind ? sgt : (wgt + (size_t)e * I_DIM * H_DIM);
    const u16* ub = kind ? sut : (wut + (size_t)e * I_DIM * H_DIM);
    int c = cnt[e];

    const u16 *gA[2], *gG, *gU;
    u16 *dA[2], *dG, *dU;
    #pragma unroll
    for (int jj = 0; jj < 2; ++jj) {
        int call = w * 2 + jj;
        int row = call * 16 + srow;               // 0..127
        int gc = scp ^ ((row >> 1) & 3);
        int tok;
        if (kind) tok = mt * 128 + row;
        else {
            int p = mt * 128 + row;
            int pc = p < c ? p : c - 1;
            tok = elist[e * T_TOK + pc] >> 1;
        }
        gA[jj] = xb + (size_t)tok * H_DIM + gc * 8;
        dA[jj] = lA + call * 512;
    }
    {
        int row = w * 16 + srow;                  // 0..63
        int gc = scp ^ ((row >> 1) & 3);
        gG = gb + (size_t)(cb * 64 + row) * H_DIM + gc * 8;
        gU = ub + (size_t)(cb * 64 + row) * H_DIM + gc * 8;
        dG = lG + w * 512;
        dU = lU + w * 512;
    }

    int wr = w >> 1, wc = w & 1;
    int quad = lane >> 4, l15 = lane & 15;
    const u16 *fA[4], *fG[2], *fU[2];
    #pragma unroll
    for (int i = 0; i < 4; ++i) {
        int r = wr * 64 + i * 16 + l15;
        fA[i] = lA + r * 32 + (quad ^ ((r >> 1) & 3)) * 8;
    }
    #pragma unroll
    for (int j = 0; j < 2; ++j) {
        int n = wc * 32 + j * 16 + l15;
        fG[j] = lG + n * 32 + (quad ^ ((n >> 1) & 3)) * 8;
        fU[j] = lU + n * 32 + (quad ^ ((n >> 1) & 3)) * 8;
    }

    floatx4 accg[4][2], accu[4][2];
    #pragma unroll
    for (int i = 0; i < 4; ++i)
        #pragma unroll
        for (int j = 0; j < 2; ++j)
            #pragma unroll
            for (int r = 0; r < 4; ++r) { accg[i][j][r] = 0.f; accu[i][j][r] = 0.f; }

    for (int s = 0; s < H_DIM / 32; ++s) {
        gld16(gA[0], dA[0]); gld16(gA[1], dA[1]);
        gld16(gG, dG); gld16(gU, dU);
        gA[0] += 32; gA[1] += 32; gG += 32; gU += 32;
        __syncthreads();
        short8 a[4], g[2], u[2];
        #pragma unroll
        for (int i = 0; i < 4; ++i) a[i] = *(const short8*)fA[i];
        #pragma unroll
        for (int j = 0; j < 2; ++j) { g[j] = *(const short8*)fG[j]; u[j] = *(const short8*)fU[j]; }
        #pragma unroll
        for (int i = 0; i < 4; ++i)
            #pragma unroll
            for (int j = 0; j < 2; ++j) {
                accg[i][j] = __builtin_amdgcn_mfma_f32_16x16x32_bf16(a[i], g[j], accg[i][j], 0, 0, 0);
                accu[i][j] = __builtin_amdgcn_mfma_f32_16x16x32_bf16(a[i], u[j], accu[i][j], 0, 0, 0);
            }
        __syncthreads();
    }

    u16* obase = kind ? (sact + (size_t)(mt * 128) * IS_DIM)
                      : (act + (size_t)(base[e] + mt * 128) * I_DIM);
    int old = kind ? IS_DIM : I_DIM;
    #pragma unroll
    for (int i = 0; i < 4; ++i)
        #pragma unroll
        for (int j = 0; j < 2; ++j)
            #pragma unroll
            for (int r = 0; r < 4; ++r) {
                int row = wr * 64 + i * 16 + quad * 4 + r;
                int col = cb * 64 + wc * 32 + j * 16 + l15;
                float gg = accg[i][j][r], uu = accu[i][j][r];
                float aa = gg / (1.f + __expf(-gg)) * uu;   // silu(g)*u
                obase[(size_t)row * old + col] = f2bf(aa);
            }
}

// ---------------------------------------------------------------------------
// Fused down GEMM. Block = 128 rows x 64 cols. Routed K=512 -> y0/y1 scatter;
// shared K=1024 -> f32 out. nb 0..15 both.
// ---------------------------------------------------------------------------
__global__ __launch_bounds__(256, 2)
void k_down(const u16* act, const u16* sact, const u16* wdt, const u16* sdt,
            const int* elist, const int* cnt, const int* base, const float* topkw,
            const int* dn_desc, const int* dn_count,
            u16* y0, u16* y1, float* out)
{
    int bi = blockIdx.x;
    if (bi >= *dn_count) return;
    int d = dn_desc[bi];
    int kind = ((unsigned)d) >> 31;
    int e = (d >> 16) & 15, mt = (d >> 8) & 255, nb = d & 255;

    __shared__ u16 lA[128 * 32], lB[64 * 32];
    int tid = threadIdx.x, lane = tid & 63, w = tid >> 6;
    int srow = lane >> 2, scp = lane & 3;

    int K = kind ? IS_DIM : I_DIM;
    const u16* ab = kind ? (sact + (size_t)(mt * 128) * IS_DIM)
                         : (act + (size_t)(base[e] + mt * 128) * I_DIM);
    const u16* bb = kind ? (sdt + (size_t)(nb * 64) * IS_DIM)
                         : (wdt + ((size_t)e * H_DIM + nb * 64) * I_DIM);
    int c = cnt[e];

    const u16 *gA[2], *gB;
    u16 *dA[2], *dB;
    #pragma unroll
    for (int jj = 0; jj < 2; ++jj) {
        int call = w * 2 + jj;
        int row = call * 16 + srow;
        int gc = scp ^ ((row >> 1) & 3);
        gA[jj] = ab + (size_t)row * K + gc * 8;
        dA[jj] = lA + call * 512;
    }
    {
        int row = w * 16 + srow;
        int gc = scp ^ ((row >> 1) & 3);
        gB = bb + (size_t)row * K + gc * 8;
        dB = lB + w * 512;
    }

    int wr = w >> 1, wc = w & 1;
    int quad = lane >> 4, l15 = lane & 15;
    const u16 *fA[4], *fB[2];
    #pragma unroll
    for (int i = 0; i < 4; ++i) {
        int r = wr * 64 + i * 16 + l15;
        fA[i] = lA + r * 32 + (quad ^ ((r >> 1) & 3)) * 8;
    }
    #pragma unroll
    for (int j = 0; j < 2; ++j) {
        int n = wc * 32 + j * 16 + l15;
        fB[j] = lB + n * 32 + (quad ^ ((n >> 1) & 3)) * 8;
    }

    floatx4 acc[4][2];
    #pragma unroll
    for (int i = 0; i < 4; ++i)
        #pragma unroll
        for (int j = 0; j < 2; ++j)
            #pragma unroll
            for (int r = 0; r < 4; ++r) acc[i][j][r] = 0.f;

    int steps = K >> 5;
    for (int s = 0; s < steps; ++s) {
        gld16(gA[0], dA[0]); gld16(gA[1], dA[1]); gld16(gB, dB);
        gA[0] += 32; gA[1] += 32; gB += 32;
        __syncthreads();
        short8 a[4], b[2];
        #pragma unroll
        for (int i = 0; i < 4; ++i) a[i] = *(const short8*)fA[i];
        #pragma unroll
        for (int j = 0; j < 2; ++j) b[j] = *(const short8*)fB[j];
        #pragma unroll
        for (int i = 0; i < 4; ++i)
            #pragma unroll
            for (int j = 0; j < 2; ++j)
                acc[i][j] = __builtin_amdgcn_mfma_f32_16x16x32_bf16(a[i], b[j], acc[i][j], 0, 0, 0);
        __syncthreads();
    }

    if (kind) {
        #pragma unroll
        for (int i = 0; i < 4; ++i)
            #pragma unroll
            for (int j = 0; j < 2; ++j)
                #pragma unroll
                for (int r = 0; r < 4; ++r) {
                    int row = mt * 128 + wr * 64 + i * 16 + quad * 4 + r;
                    int col = nb * 64 + wc * 32 + j * 16 + l15;
                    out[(size_t)row * H_DIM + col] = acc[i][j][r];
                }
    } else {
        #pragma unroll
        for (int i = 0; i < 4; ++i)
            #pragma unroll
            for (int r = 0; r < 4; ++r) {
                int row = wr * 64 + i * 16 + quad * 4 + r;
                int p = mt * 128 + row;
                if (p < c) {
                    int ent = elist[e * T_TOK + p];
                    int t = ent >> 1, sl = ent & 1;
                    float wt = topkw[t * 2 + sl];
                    u16* yb = sl ? y1 : y0;
                    #pragma unroll
                    for (int j = 0; j < 2; ++j) {
                        int col = nb * 64 + wc * 32 + j * 16 + l15;
                        yb[(size_t)t * H_DIM + col] = f2bf(wt * acc[i][j][r]);
                    }
                }
            }
    }
}

// Final combine: out += y0 + y1 (out already holds shared-expert result).
__global__ __launch_bounds__(256)
void k_final(float* out, const u16* y0, const u16* y1)
{
    int i = blockIdx.x * 256 + threadIdx.x;
    float4 o = ((const float4*)out)[i];
    uint2 a = ((const uint2*)y0)[i];
    uint2 b = ((const uint2*)y1)[i];
    const u16* pa = (const u16*)&a;
    const u16* pb = (const u16*)&b;
    o.x += bf2f(pa[0]) + bf2f(pb[0]);
    o.y += bf2f(pa[1]) + bf2f(pb[1]);
    o.z += bf2f(pa[2]) + bf2f(pb[2]);
    o.w += bf2f(pa[3]) + bf2f(pb[3]);
    ((float4*)out)[i] = o;
}

// ---------------------------------------------------------------------------
extern "C" void kernel_launch(void* const* d_in, const int* in_sizes, int n_in,
                              void* d_out, int out_size, void* d_ws, size_t ws_size,
                              hipStream_t stream)
{
    const float* x  = (const float*)d_in[0];
    const float* rw = (const float*)d_in[1];
    const float* wg = (const float*)d_in[2];
    const float* wu = (const float*)d_in[3];
    const float* wd = (const float*)d_in[4];
    const float* sg = (const float*)d_in[5];
    const float* su = (const float*)d_in[6];
    const float* sd = (const float*)d_in[7];
    float* out = (float*)d_out;

    char* ws = (char*)d_ws;
    const size_t MB = 1024ull * 1024ull;
    u16* wgt  = (u16*)(ws);            // [E][I][H] bf16  16 MB
    u16* wut  = (u16*)(ws + 16 * MB);  // [E][I][H]       16 MB
    u16* wdt  = (u16*)(ws + 32 * MB);  // [E][H][I]       16 MB
    u16* sgt  = (u16*)(ws + 48 * MB);  // [IS][H]          2 MB
    u16* sut  = (u16*)(ws + 50 * MB);  // [IS][H]          2 MB
    u16* sdt  = (u16*)(ws + 52 * MB);  // [H][IS]          2 MB
    u16* xb   = (u16*)(ws + 54 * MB);  // [T][H] bf16      8 MB
    u16* act  = (u16*)(ws + 62 * MB);  // [<=10240][I]    10 MB (128-padded rows)
    u16* sact = (u16*)(ws + 72 * MB);  // [T][IS]          8 MB
    u16* y0   = (u16*)(ws + 80 * MB);  // [T][H] slot0     8 MB
    u16* y1   = (u16*)(ws + 88 * MB);  // [T][H] slot1     8 MB
    float* topkw  = (float*)(ws + 96 * MB);            // [T][2]
    int* elist    = (int*)(ws + 96 * MB + 64 * 1024);  // [E][T]
    int* cnt      = (int*)(ws + 97 * MB);              // [E]
    int* base     = (int*)(ws + 97 * MB + 256);        // [E]
    int* gu_count = (int*)(ws + 97 * MB + 512);
    int* dn_count = (int*)(ws + 97 * MB + 516);
    int* gu_desc  = (int*)(ws + 97 * MB + 1024);       // <=1152 ints
    int* dn_desc  = (int*)(ws + 97 * MB + 8192);       // <=1792 ints

    hipMemsetAsync(cnt, 0, E_NUM * sizeof(int), stream);
    k_transpose<<<6912, 256, 0, stream>>>(wg, wu, wd, sg, su, sd,
                                          wgt, wut, wdt, sgt, sut, sdt);
    k_xconv<<<T_TOK * H_DIM / 4 / 256, 256, 0, stream>>>(x, xb);
    k_router<<<T_TOK / 4, 256, 0, stream>>>(x, rw, topkw, elist, cnt);
    k_prefix<<<1, 64, 0, stream>>>(cnt, base, gu_desc, gu_count, dn_desc, dn_count);
    k_gateup<<<MAX_GU, 256, 0, stream>>>(xb, wgt, wut, sgt, sut,
                                         elist, cnt, base, gu_desc, gu_count,
                                         act, sact);
    k_down<<<MAX_DN, 256, 0, stream>>>(act, sact, wdt, sdt,
                                       elist, cnt, base, topkw,
                                       dn_desc, dn_count, y0, y1, out);
    k_final<<<T_TOK * H_DIM / 4 / 256, 256, 0, stream>>>(out, y0, y1);
}

// Round 7
// 293.915 us; speedup vs baseline: 3.9766x; 1.3063x over previous
//
#include <hip/hip_runtime.h>
#include <hip/hip_bf16.h>
#include <math.h>

// SigmaMoE: T=4096 tokens, H=1024, I=512, E=16 experts, top-2, shared IS=1024.
// Inputs/outputs FLOAT32; internal GEMMs bf16 MFMA 16x16x32, 128x64 tiles,
// BK=64 (2 chunks per barrier), global_load_lds width-16, XOR-swizzled LDS.
// R7: per-expert counters padded to separate cache lines (R6 post-mortem:
// 8192 same-line atomics = 110us serialization); BK=64 halves barrier drains.
#define H_DIM 1024
#define I_DIM 512
#define E_NUM 16
#define T_TOK 4096
#define IS_DIM 1024
#define MAX_GU 1152   // 32*16 shared + <=80 routed m-tiles * 8
#define MAX_DN 1792   // 32*16 shared + <=80 routed m-tiles * 16
#define CSTR 32       // cnt stride in ints (128B = own cache line per expert)

typedef unsigned short u16;
typedef __attribute__((ext_vector_type(8))) short short8;   // 8 x bf16 frag (16B)
typedef __attribute__((ext_vector_type(4))) float floatx4;  // 16x16 acc

__device__ __forceinline__ float bf2f(u16 u) {
    union { unsigned int u; float f; } c; c.u = ((unsigned int)u) << 16; return c.f;
}
__device__ __forceinline__ u16 f2bf(float f) {
    union { float f; unsigned int u; } c; c.f = f;
    unsigned int r = (c.u + 0x7fffu + ((c.u >> 16) & 1u)) >> 16;
    return (u16)r;
}
// async global->LDS, 16B/lane; LDS dest = wave-uniform base + lane*16.
__device__ __forceinline__ void gld16(const u16* g, u16* l) {
    __builtin_amdgcn_global_load_lds(
        (const __attribute__((address_space(1))) unsigned int*)g,
        (__attribute__((address_space(3))) unsigned int*)l, 16, 0, 0);
}

// ---------------------------------------------------------------------------
// Weight convert+transpose: f32 K-major -> bf16 N-major. (unchanged, works)
// ---------------------------------------------------------------------------
__global__ __launch_bounds__(256)
void k_transpose(const float* wg, const float* wu, const float* wd,
                 const float* sg, const float* su, const float* sd,
                 u16* wgt, u16* wut, u16* wdt, u16* sgt, u16* sut, u16* sdt)
{
    int bx = blockIdx.x;
    const float* src; u16* dst; int R, C, local;
    if (bx < 2048)      { src = wg; dst = wgt; R = 1024; C = 512;  local = bx; }
    else if (bx < 4096) { src = wu; dst = wut; R = 1024; C = 512;  local = bx - 2048; }
    else if (bx < 6144) { src = wd; dst = wdt; R = 512;  C = 1024; local = bx - 4096; }
    else if (bx < 6400) { src = sg; dst = sgt; R = 1024; C = 1024; local = bx - 6144; }
    else if (bx < 6656) { src = su; dst = sut; R = 1024; C = 1024; local = bx - 6400; }
    else                { src = sd; dst = sdt; R = 1024; C = 1024; local = bx - 6656; }
    int tpm = (R >> 6) * (C >> 6);
    int mat = local / tpm;
    int tl_ = local - mat * tpm;
    int tcn = C >> 6;
    int tr = tl_ / tcn, tc = tl_ - (tl_ / tcn) * tcn;
    src += (size_t)mat * R * C;
    dst += (size_t)mat * R * C;

    __shared__ u16 tile[64][65];
    int t = threadIdx.x;
    int r0 = t >> 2, c0 = (t & 3) * 16;
    const float* sp = src + (size_t)(tr * 64 + r0) * C + tc * 64 + c0;
    #pragma unroll
    for (int j = 0; j < 16; j += 4) {
        float4 v = *(const float4*)(sp + j);
        tile[r0][c0 + j + 0] = f2bf(v.x);
        tile[r0][c0 + j + 1] = f2bf(v.y);
        tile[r0][c0 + j + 2] = f2bf(v.z);
        tile[r0][c0 + j + 3] = f2bf(v.w);
    }
    __syncthreads();
    int cW = t >> 2, rW = (t & 3) * 16;
    u16 tmp[16];
    #pragma unroll
    for (int j = 0; j < 16; ++j) tmp[j] = tile[rW + j][cW];
    u16* dp = dst + (size_t)(tc * 64 + cW) * R + tr * 64 + rW;
    *(uint4*)(dp)     = *(const uint4*)(tmp);
    *(uint4*)(dp + 8) = *(const uint4*)(tmp + 8);
}

// f32 -> bf16 copy of x.
__global__ __launch_bounds__(256)
void k_xconv(const float* x, u16* xb)
{
    int i = blockIdx.x * 256 + threadIdx.x;
    float4 v = ((const float4*)x)[i];
    u16 o[4] = { f2bf(v.x), f2bf(v.y), f2bf(v.z), f2bf(v.w) };
    ((uint2*)xb)[i] = *(const uint2*)o;
}

// ---------------------------------------------------------------------------
// Router. Counters padded one cache line per expert -> 16 independent atomic
// streams instead of one serialized line.
// ---------------------------------------------------------------------------
__global__ __launch_bounds__(256)
void k_router(const float* x, const float* rw, float* topkw, int* elist, int* cnt)
{
    int lane = threadIdx.x & 63;
    int wv = threadIdx.x >> 6;
    int t = blockIdx.x * 4 + wv;
    const float* xr = x + (size_t)t * H_DIM;
    float xv[16];
    #pragma unroll
    for (int j = 0; j < 16; ++j) xv[j] = xr[j * 64 + lane];
    float sc[E_NUM];
    #pragma unroll
    for (int e = 0; e < E_NUM; ++e) sc[e] = 0.f;
    #pragma unroll
    for (int e = 0; e < E_NUM; ++e) {
        const float* rr = rw + e * H_DIM;
        #pragma unroll
        for (int j = 0; j < 16; ++j) sc[e] += xv[j] * rr[j * 64 + lane];
    }
    #pragma unroll
    for (int off = 32; off > 0; off >>= 1) {
        float tmp[E_NUM];
        #pragma unroll
        for (int e = 0; e < E_NUM; ++e) tmp[e] = __shfl_xor(sc[e], off, 64);
        #pragma unroll
        for (int e = 0; e < E_NUM; ++e) sc[e] += tmp[e];
    }
    if (lane == 0) {
        float b1 = -1e30f, b2 = -1e30f; int i1 = 0, i2 = 0;
        #pragma unroll
        for (int e = 0; e < E_NUM; ++e) {
            if (sc[e] > b1) { b2 = b1; i2 = i1; b1 = sc[e]; i1 = e; }
            else if (sc[e] > b2) { b2 = sc[e]; i2 = e; }
        }
        float w1 = 1.f / (1.f + __expf(b2 - b1));
        float w2 = 1.f - w1;
        topkw[t * 2]     = w1;
        topkw[t * 2 + 1] = w2;
        int p1 = atomicAdd(&cnt[i1 * CSTR], 1); elist[i1 * T_TOK + p1] = (t << 1);
        int p2 = atomicAdd(&cnt[i2 * CSTR], 1); elist[i2 * T_TOK + p2] = (t << 1) | 1;
    }
}

// ---------------------------------------------------------------------------
// Prefix + tile-list builder (parallel, 1 block of 64).
// desc = kind<<31 | e<<16 | mt<<8 | cb.  Shared (heavy) tiles first.
// ---------------------------------------------------------------------------
__global__ void k_prefix(const int* cnt, int* base,
                         int* gu_desc, int* gu_count, int* dn_desc, int* dn_count)
{
    __shared__ int mts_s[E_NUM], moff_s[E_NUM];
    int lane = threadIdx.x;  // 64 threads
    if (lane == 0) {
        int b = 0, mo = 0;
        for (int e = 0; e < E_NUM; ++e) {
            int mts = (cnt[e * CSTR] + 127) >> 7;
            base[e] = b; b += mts << 7;
            mts_s[e] = mts; moff_s[e] = mo; mo += mts;
        }
        *gu_count = 512 + mo * 8;
        *dn_count = 512 + mo * 16;
    }
    __syncthreads();
    for (int i = lane; i < 512; i += 64) {
        int mt = i >> 4, cb = i & 15;
        int d = (1 << 31) | (mt << 8) | cb;
        gu_desc[i] = d;
        dn_desc[i] = d;
    }
    if (lane < E_NUM) {
        int e = lane, mts = mts_s[e], mo = moff_s[e];
        for (int mt = 0; mt < mts; ++mt) {
            #pragma unroll
            for (int cb = 0; cb < 8; ++cb)
                gu_desc[512 + (mo + mt) * 8 + cb] = (e << 16) | (mt << 8) | cb;
            #pragma unroll
            for (int nb = 0; nb < 16; ++nb)
                dn_desc[512 + (mo + mt) * 16 + nb] = (e << 16) | (mt << 8) | nb;
        }
    }
}

// ---------------------------------------------------------------------------
// Fused gate/up GEMM (routed + shared). Block = 128 rows x 64 cols of both
// g and u. BK=64: 2 k-chunks staged per barrier, 32 MFMA per barrier.
// ---------------------------------------------------------------------------
__global__ __launch_bounds__(256, 2)
void k_gateup(const u16* xb, const u16* wgt, const u16* wut,
              const u16* sgt, const u16* sut,
              const int* elist, const int* cnt, const int* base,
              const int* gu_desc, const int* gu_count,
              u16* act, u16* sact)
{
    int bi = blockIdx.x;
    if (bi >= *gu_count) return;
    int d = gu_desc[bi];
    int kind = ((unsigned)d) >> 31;          // 0 routed, 1 shared
    int e = (d >> 16) & 15, mt = (d >> 8) & 255, cb = d & 255;

    __shared__ u16 lA[128 * 64], lG[64 * 64], lU[64 * 64];   // chunk-major halves
    int tid = threadIdx.x, lane = tid & 63, w = tid >> 6;
    int srow = lane >> 2, scp = lane & 3;

    const u16* gb = kind ? sgt : (wgt + (size_t)e * I_DIM * H_DIM);
    const u16* ub = kind ? sut : (wut + (size_t)e * I_DIM * H_DIM);
    int c = cnt[e * CSTR];

    const u16 *gA[2], *gG, *gU;
    u16 *dA[2], *dG, *dU;
    #pragma unroll
    for (int jj = 0; jj < 2; ++jj) {
        int call = w * 2 + jj;
        int row = call * 16 + srow;               // 0..127
        int gc = scp ^ ((row >> 1) & 3);
        int tok;
        if (kind) tok = mt * 128 + row;
        else {
            int p = mt * 128 + row;
            int pc = p < c ? p : c - 1;
            tok = elist[e * T_TOK + pc] >> 1;
        }
        gA[jj] = xb + (size_t)tok * H_DIM + gc * 8;
        dA[jj] = lA + call * 512;
    }
    {
        int row = w * 16 + srow;                  // 0..63
        int gc = scp ^ ((row >> 1) & 3);
        gG = gb + (size_t)(cb * 64 + row) * H_DIM + gc * 8;
        gU = ub + (size_t)(cb * 64 + row) * H_DIM + gc * 8;
        dG = lG + w * 512;
        dU = lU + w * 512;
    }

    int wr = w >> 1, wc = w & 1;
    int quad = lane >> 4, l15 = lane & 15;
    const u16 *fA[4], *fG[2], *fU[2];
    #pragma unroll
    for (int i = 0; i < 4; ++i) {
        int r = wr * 64 + i * 16 + l15;
        fA[i] = lA + r * 32 + (quad ^ ((r >> 1) & 3)) * 8;
    }
    #pragma unroll
    for (int j = 0; j < 2; ++j) {
        int n = wc * 32 + j * 16 + l15;
        fG[j] = lG + n * 32 + (quad ^ ((n >> 1) & 3)) * 8;
        fU[j] = lU + n * 32 + (quad ^ ((n >> 1) & 3)) * 8;
    }

    floatx4 accg[4][2], accu[4][2];
    #pragma unroll
    for (int i = 0; i < 4; ++i)
        #pragma unroll
        for (int j = 0; j < 2; ++j)
            #pragma unroll
            for (int r = 0; r < 4; ++r) { accg[i][j][r] = 0.f; accu[i][j][r] = 0.f; }

    for (int s = 0; s < H_DIM / 64; ++s) {
        #pragma unroll
        for (int q = 0; q < 2; ++q) {
            gld16(gA[0] + q * 32, dA[0] + q * 4096);
            gld16(gA[1] + q * 32, dA[1] + q * 4096);
            gld16(gG + q * 32, dG + q * 2048);
            gld16(gU + q * 32, dU + q * 2048);
        }
        gA[0] += 64; gA[1] += 64; gG += 64; gU += 64;
        __syncthreads();
        #pragma unroll
        for (int q = 0; q < 2; ++q) {
            short8 a[4], g[2], u[2];
            #pragma unroll
            for (int i = 0; i < 4; ++i) a[i] = *(const short8*)(fA[i] + q * 4096);
            #pragma unroll
            for (int j = 0; j < 2; ++j) {
                g[j] = *(const short8*)(fG[j] + q * 2048);
                u[j] = *(const short8*)(fU[j] + q * 2048);
            }
            #pragma unroll
            for (int i = 0; i < 4; ++i)
                #pragma unroll
                for (int j = 0; j < 2; ++j) {
                    accg[i][j] = __builtin_amdgcn_mfma_f32_16x16x32_bf16(a[i], g[j], accg[i][j], 0, 0, 0);
                    accu[i][j] = __builtin_amdgcn_mfma_f32_16x16x32_bf16(a[i], u[j], accu[i][j], 0, 0, 0);
                }
        }
        __syncthreads();
    }

    u16* obase = kind ? (sact + (size_t)(mt * 128) * IS_DIM)
                      : (act + (size_t)(base[e] + mt * 128) * I_DIM);
    int old = kind ? IS_DIM : I_DIM;
    #pragma unroll
    for (int i = 0; i < 4; ++i)
        #pragma unroll
        for (int j = 0; j < 2; ++j)
            #pragma unroll
            for (int r = 0; r < 4; ++r) {
                int row = wr * 64 + i * 16 + quad * 4 + r;
                int col = cb * 64 + wc * 32 + j * 16 + l15;
                float gg = accg[i][j][r], uu = accu[i][j][r];
                float aa = gg / (1.f + __expf(-gg)) * uu;   // silu(g)*u
                obase[(size_t)row * old + col] = f2bf(aa);
            }
}

// ---------------------------------------------------------------------------
// Fused down GEMM. Block = 128 rows x 64 cols, BK=64. Routed K=512 -> y0/y1
// scatter; shared K=1024 -> f32 out.
// ---------------------------------------------------------------------------
__global__ __launch_bounds__(256, 2)
void k_down(const u16* act, const u16* sact, const u16* wdt, const u16* sdt,
            const int* elist, const int* cnt, const int* base, const float* topkw,
            const int* dn_desc, const int* dn_count,
            u16* y0, u16* y1, float* out)
{
    int bi = blockIdx.x;
    if (bi >= *dn_count) return;
    int d = dn_desc[bi];
    int kind = ((unsigned)d) >> 31;
    int e = (d >> 16) & 15, mt = (d >> 8) & 255, nb = d & 255;

    __shared__ u16 lA[128 * 64], lB[64 * 64];
    int tid = threadIdx.x, lane = tid & 63, w = tid >> 6;
    int srow = lane >> 2, scp = lane & 3;

    int K = kind ? IS_DIM : I_DIM;
    const u16* ab = kind ? (sact + (size_t)(mt * 128) * IS_DIM)
                         : (act + (size_t)(base[e] + mt * 128) * I_DIM);
    const u16* bb = kind ? (sdt + (size_t)(nb * 64) * IS_DIM)
                         : (wdt + ((size_t)e * H_DIM + nb * 64) * I_DIM);
    int c = cnt[e * CSTR];

    const u16 *gA[2], *gB;
    u16 *dA[2], *dB;
    #pragma unroll
    for (int jj = 0; jj < 2; ++jj) {
        int call = w * 2 + jj;
        int row = call * 16 + srow;
        int gc = scp ^ ((row >> 1) & 3);
        gA[jj] = ab + (size_t)row * K + gc * 8;
        dA[jj] = lA + call * 512;
    }
    {
        int row = w * 16 + srow;
        int gc = scp ^ ((row >> 1) & 3);
        gB = bb + (size_t)row * K + gc * 8;
        dB = lB + w * 512;
    }

    int wr = w >> 1, wc = w & 1;
    int quad = lane >> 4, l15 = lane & 15;
    const u16 *fA[4], *fB[2];
    #pragma unroll
    for (int i = 0; i < 4; ++i) {
        int r = wr * 64 + i * 16 + l15;
        fA[i] = lA + r * 32 + (quad ^ ((r >> 1) & 3)) * 8;
    }
    #pragma unroll
    for (int j = 0; j < 2; ++j) {
        int n = wc * 32 + j * 16 + l15;
        fB[j] = lB + n * 32 + (quad ^ ((n >> 1) & 3)) * 8;
    }

    floatx4 acc[4][2];
    #pragma unroll
    for (int i = 0; i < 4; ++i)
        #pragma unroll
        for (int j = 0; j < 2; ++j)
            #pragma unroll
            for (int r = 0; r < 4; ++r) acc[i][j][r] = 0.f;

    int steps = K >> 6;
    for (int s = 0; s < steps; ++s) {
        #pragma unroll
        for (int q = 0; q < 2; ++q) {
            gld16(gA[0] + q * 32, dA[0] + q * 4096);
            gld16(gA[1] + q * 32, dA[1] + q * 4096);
            gld16(gB + q * 32, dB + q * 2048);
        }
        gA[0] += 64; gA[1] += 64; gB += 64;
        __syncthreads();
        #pragma unroll
        for (int q = 0; q < 2; ++q) {
            short8 a[4], b[2];
            #pragma unroll
            for (int i = 0; i < 4; ++i) a[i] = *(const short8*)(fA[i] + q * 4096);
            #pragma unroll
            for (int j = 0; j < 2; ++j) b[j] = *(const short8*)(fB[j] + q * 2048);
            #pragma unroll
            for (int i = 0; i < 4; ++i)
                #pragma unroll
                for (int j = 0; j < 2; ++j)
                    acc[i][j] = __builtin_amdgcn_mfma_f32_16x16x32_bf16(a[i], b[j], acc[i][j], 0, 0, 0);
        }
        __syncthreads();
    }

    if (kind) {
        #pragma unroll
        for (int i = 0; i < 4; ++i)
            #pragma unroll
            for (int j = 0; j < 2; ++j)
                #pragma unroll
                for (int r = 0; r < 4; ++r) {
                    int row = mt * 128 + wr * 64 + i * 16 + quad * 4 + r;
                    int col = nb * 64 + wc * 32 + j * 16 + l15;
                    out[(size_t)row * H_DIM + col] = acc[i][j][r];
                }
    } else {
        #pragma unroll
        for (int i = 0; i < 4; ++i)
            #pragma unroll
            for (int r = 0; r < 4; ++r) {
                int row = wr * 64 + i * 16 + quad * 4 + r;
                int p = mt * 128 + row;
                if (p < c) {
                    int ent = elist[e * T_TOK + p];
                    int t = ent >> 1, sl = ent & 1;
                    float wt = topkw[t * 2 + sl];
                    u16* yb = sl ? y1 : y0;
                    #pragma unroll
                    for (int j = 0; j < 2; ++j) {
                        int col = nb * 64 + wc * 32 + j * 16 + l15;
                        yb[(size_t)t * H_DIM + col] = f2bf(wt * acc[i][j][r]);
                    }
                }
            }
    }
}

// Final combine: out += y0 + y1 (out already holds shared-expert result).
__global__ __launch_bounds__(256)
void k_final(float* out, const u16* y0, const u16* y1)
{
    int i = blockIdx.x * 256 + threadIdx.x;
    float4 o = ((const float4*)out)[i];
    uint2 a = ((const uint2*)y0)[i];
    uint2 b = ((const uint2*)y1)[i];
    const u16* pa = (const u16*)&a;
    const u16* pb = (const u16*)&b;
    o.x += bf2f(pa[0]) + bf2f(pb[0]);
    o.y += bf2f(pa[1]) + bf2f(pb[1]);
    o.z += bf2f(pa[2]) + bf2f(pb[2]);
    o.w += bf2f(pa[3]) + bf2f(pb[3]);
    ((float4*)out)[i] = o;
}

// ---------------------------------------------------------------------------
extern "C" void kernel_launch(void* const* d_in, const int* in_sizes, int n_in,
                              void* d_out, int out_size, void* d_ws, size_t ws_size,
                              hipStream_t stream)
{
    const float* x  = (const float*)d_in[0];
    const float* rw = (const float*)d_in[1];
    const float* wg = (const float*)d_in[2];
    const float* wu = (const float*)d_in[3];
    const float* wd = (const float*)d_in[4];
    const float* sg = (const float*)d_in[5];
    const float* su = (const float*)d_in[6];
    const float* sd = (const float*)d_in[7];
    float* out = (float*)d_out;

    char* ws = (char*)d_ws;
    const size_t MB = 1024ull * 1024ull;
    u16* wgt  = (u16*)(ws);            // [E][I][H] bf16  16 MB
    u16* wut  = (u16*)(ws + 16 * MB);  // [E][I][H]       16 MB
    u16* wdt  = (u16*)(ws + 32 * MB);  // [E][H][I]       16 MB
    u16* sgt  = (u16*)(ws + 48 * MB);  // [IS][H]          2 MB
    u16* sut  = (u16*)(ws + 50 * MB);  // [IS][H]          2 MB
    u16* sdt  = (u16*)(ws + 52 * MB);  // [H][IS]          2 MB
    u16* xb   = (u16*)(ws + 54 * MB);  // [T][H] bf16      8 MB
    u16* act  = (u16*)(ws + 62 * MB);  // [<=10240][I]    10 MB (128-padded rows)
    u16* sact = (u16*)(ws + 72 * MB);  // [T][IS]          8 MB
    u16* y0   = (u16*)(ws + 80 * MB);  // [T][H] slot0     8 MB
    u16* y1   = (u16*)(ws + 88 * MB);  // [T][H] slot1     8 MB
    float* topkw  = (float*)(ws + 96 * MB);            // [T][2]
    int* elist    = (int*)(ws + 96 * MB + 64 * 1024);  // [E][T]
    int* cnt      = (int*)(ws + 97 * MB);              // [E] stride CSTR
    int* base     = (int*)(ws + 97 * MB + 8192);       // [E]
    int* gu_count = (int*)(ws + 97 * MB + 8448);
    int* dn_count = (int*)(ws + 97 * MB + 8452);
    int* gu_desc  = (int*)(ws + 97 * MB + 16384);      // <=1152 ints
    int* dn_desc  = (int*)(ws + 97 * MB + 32768);      // <=1792 ints

    hipMemsetAsync(cnt, 0, E_NUM * CSTR * sizeof(int), stream);
    k_transpose<<<6912, 256, 0, stream>>>(wg, wu, wd, sg, su, sd,
                                          wgt, wut, wdt, sgt, sut, sdt);
    k_xconv<<<T_TOK * H_DIM / 4 / 256, 256, 0, stream>>>(x, xb);
    k_router<<<T_TOK / 4, 256, 0, stream>>>(x, rw, topkw, elist, cnt);
    k_prefix<<<1, 64, 0, stream>>>(cnt, base, gu_desc, gu_count, dn_desc, dn_count);
    k_gateup<<<MAX_GU, 256, 0, stream>>>(xb, wgt, wut, sgt, sut,
                                         elist, cnt, base, gu_desc, gu_count,
                                         act, sact);
    k_down<<<MAX_DN, 256, 0, stream>>>(act, sact, wdt, sdt,
                                       elist, cnt, base, topkw,
                                       dn_desc, dn_count, y0, y1, out);
    k_final<<<T_TOK * H_DIM / 4 / 256, 256, 0, stream>>>(out, y0, y1);
}